// Round 9
// baseline (367.401 us; speedup 1.0000x reference)
//
#include <hip/hip_runtime.h>
#include <hip/hip_bf16.h>
#include <math.h>

// Static maxima (LDS sizing); actual dims derived at runtime from in_sizes.
#define LMAX 8192
#define KGAUSS 25

#define PI_F 3.14159265358979323846f
#define TWO_PI_F 6.28318530717958647692f

typedef __hip_bfloat16 bf16;
typedef unsigned short u16;
typedef short bf16x8 __attribute__((ext_vector_type(8)));
typedef float f32x4 __attribute__((ext_vector_type(4)));

__device__ __forceinline__ float b2f(bf16 v) { return __bfloat162float(v); }
__device__ __forceinline__ bf16 f2b(float v) { return __float2bfloat16(v); }
__device__ __forceinline__ float rdv(const void* p, long i, int isb) {
  return isb ? b2f(((const bf16*)p)[i]) : ((const float*)p)[i];
}

__device__ __forceinline__ void async16(const void* g, void* l) {
#if __has_builtin(__builtin_amdgcn_global_load_lds)
  __builtin_amdgcn_global_load_lds((const __attribute__((address_space(1))) void*)g,
                                   (__attribute__((address_space(3))) void*)l, 16, 0, 0);
#else
  *(uint4*)l = *(const uint4*)g;
#endif
}

// complex helpers for the FFT
__device__ __forceinline__ float2 f2add(float2 a, float2 b) {
  return make_float2(a.x + b.x, a.y + b.y);
}
__device__ __forceinline__ float2 f2sub(float2 a, float2 b) {
  return make_float2(a.x - b.x, a.y - b.y);
}
__device__ __forceinline__ float2 cmulc(float2 x, float2 w) {  // x * conj(w)
  return make_float2(x.x * w.x + x.y * w.y, x.y * w.x - x.x * w.y);
}
__device__ __forceinline__ float2 cmul(float2 x, float2 w) {   // x * w
  return make_float2(x.x * w.x - x.y * w.y, x.x * w.y + x.y * w.x);
}
// LDS bank swizzle for the complex FFT array (float2 index granularity).
#define ZI(i) ((i) ^ (((i) >> 4) & 15))
// LDS bank swizzle for float-array phase storage (float index granularity).
#define XS(i) ((i) ^ (((i) >> 5) & 31))

// ---------------- params + twiddle (detect inlined; one launch) -------------
// Small params -> f32 workspace, FIXED slots:
// xb@0, ib@2048, ls@4096, pw@4352, al@8448, ph@8704, ps@8960, b1@8961, b2@8962
__global__ void k_params(const void* xb, const void* ib, const void* ls, const void* pw,
                         const void* al, const void* ph, const void* ps, const void* b1,
                         const void* b2, float* pf, int* flag, float2* tw,
                         int D, int C, int KP, int L) {
  unsigned wls = ((const unsigned*)ls)[0];
  int isb = ((wls >> 16) == (wls & 0xffffu)) ? 1 : 0;
  int blk = blockIdx.x, t = threadIdx.x;
  if (blk < 64) {
    int i = blk * 256 + t;
    if (i == 0) flag[0] = isb;
    float v = 0.0f;
    if (i < D)                              v = rdv(xb, i, isb);
    else if (i >= 2048 && i < 2048 + D)     v = rdv(ib, i - 2048, isb);
    else if (i >= 4096 && i < 4096 + C)     v = rdv(ls, i - 4096, isb);
    else if (i >= 4352 && i < 4352 + C*KP)  v = rdv(pw, i - 4352, isb);
    else if (i >= 8448 && i < 8448 + C)     v = rdv(al, i - 8448, isb);
    else if (i >= 8704 && i < 8704 + C)     v = rdv(ph, i - 8704, isb);
    else if (i == 8960)                     v = rdv(ps, 0, isb);
    else if (i == 8961)                     v = rdv(b1, 0, isb);
    else if (i == 8962)                     v = rdv(b2, 0, isb);
    pf[i] = v;
  } else {
    int j = (blk - 64) * 256 + t;
    if (j < L / 2) {
      double a = 6.283185307179586476925286766559 * (double)j / (double)L;
      tw[j] = make_float2((float)cos(a), (float)sin(a));
    }
  }
}

// -------- transpose W[K][N] -> Wt[N][K] bf16, both weights in one launch -----
__global__ __launch_bounds__(256) void k_transpose2(const void* __restrict__ in0,
    const void* __restrict__ in1, bf16* __restrict__ out0, bf16* __restrict__ out1,
    const int* __restrict__ flag, int K, int N) {
  __shared__ u16 tile[64][65];
  int isb = *flag;
  const void* in = blockIdx.z ? in1 : in0;
  bf16* out = blockIdx.z ? out1 : out0;
  int r0 = blockIdx.x * 64, c0 = blockIdx.y * 64;
  int t = threadIdx.x;
#pragma unroll
  for (int i = 0; i < 16; ++i) {
    int idx = t + i * 256;
    int r = idx >> 6, cc = idx & 63;
    int gr = r0 + r; gr = gr < K ? gr : K - 1;
    int gc = c0 + cc; gc = gc < N ? gc : N - 1;
    size_t gi = (size_t)gr * N + gc;
    u16 v;
    if (isb) v = ((const u16*)in)[gi];
    else { bf16 h = f2b(((const float*)in)[gi]); v = *(u16*)&h; }
    tile[r][cc] = v;
  }
  __syncthreads();
#pragma unroll
  for (int i = 0; i < 16; ++i) {
    int idx = t + i * 256;
    int a = idx >> 6, bb = idx & 63;
    if (c0 + a < N && r0 + bb < K)
      ((u16*)out)[(size_t)(c0 + a) * K + (r0 + bb)] = tile[bb][a];
  }
}

// ------------- gaussian trend/seasonal, register sliding-window fast path ----
__global__ __launch_bounds__(256, 4) void k_decomp32(const void* __restrict__ x,
    const int* __restrict__ flag, const float* __restrict__ pf,
    float* __restrict__ seasonal, float* __restrict__ trend0,
    bf16* __restrict__ Xb, int C, int L) {
  __shared__ float xs[LMAX + LMAX / 32];  // skewed: si(i) = i + (i>>5)
  int bc = blockIdx.x, c = bc % C, b = bc / C;
  int t = threadIdx.x;
  int isb = *flag;
  for (int i = t; i < L; i += 256) {
    float xv = rdv(x, (size_t)bc * L + i, isb);
    xs[i + (i >> 5)] = xv;
    Xb[(size_t)bc * L + i] = f2b(xv);  // bf16 copy for the GEMM A-operand
  }
  float sigma = expf(pf[4096 + c]) + 1e-6f;
  float inv2s2 = 1.0f / (2.0f * sigma * sigma);
  float g[KGAUSS];
  float gs = 0.0f;
#pragma unroll
  for (int j = 0; j < KGAUSS; ++j) {
    float d = (float)(j - 12);
    float vv = expf(-(d * d) * inv2s2);
    g[j] = vv; gs += vv;
  }
  float ginv = 1.0f / (gs + 1e-12f);
#pragma unroll
  for (int j = 0; j < KGAUSS; ++j) g[j] *= ginv;
  __syncthreads();
  const int base = 32 * t;
  float v[56];  // x[base-12 .. base+43], reflect at row ends
#pragma unroll
  for (int m = 0; m < 56; ++m) {
    int idx = base + m - 12;
    idx = idx < 0 ? -idx : (idx >= L ? 2 * L - 2 - idx : idx);
    v[m] = xs[idx + (idx >> 5)];
  }
  __syncthreads();  // all xs reads done; reuse xs for seasonal
  const int sb = 33 * t;
  float aA = 0.0f, ab1 = 0.0f, ab2 = 0.0f;
  if (b == 0) {
    aA  = log1pf(expf(pf[8448 + c])) + 1e-6f;
    ab1 = log1pf(expf(pf[8961])) + 1e-6f;
    ab2 = log1pf(expf(pf[8962])) + 1e-6f;
  }
  float* trow = trend0 + (size_t)c * L;
#pragma unroll
  for (int ii = 0; ii < 32; ++ii) {
    float acc = 0.0f;
#pragma unroll
    for (int j = 0; j < KGAUSS; ++j) acc = fmaf(g[j], v[ii + j], acc);
    xs[sb + ii] = v[ii + 12] - acc;  // seasonal -> LDS
    if (b == 0) {
      float T = fminf(10.0f, fmaxf(-10.0f, acc));
      trow[base + ii] = aA * (ab1 * log1pf(expf(ab2 * T)));  // amp folded in
    }
  }
  __syncthreads();
  for (int i = t; i < L; i += 256)
    seasonal[(size_t)bc * L + i] = xs[i + (i >> 5)];
}

// ---------------- generic decomp fallback (amp folded in) --------------------
__global__ __launch_bounds__(256) void k_decomp(const void* __restrict__ x,
    const int* __restrict__ flag, const float* __restrict__ pf,
    float* __restrict__ seasonal, float* __restrict__ trend0,
    bf16* __restrict__ Xb, int C, int L) {
  __shared__ float xs[LMAX];
  int bc = blockIdx.x;
  int c = bc % C, b = bc / C;
  int t = threadIdx.x;
  int isb = *flag;
  for (int i = t; i < L; i += 256) {
    float xv = rdv(x, (size_t)bc * L + i, isb);
    xs[i] = xv;
    Xb[(size_t)bc * L + i] = f2b(xv);
  }
  float sigma = expf(pf[4096 + c]) + 1e-6f;
  float inv2s2 = 1.0f / (2.0f * sigma * sigma);
  float g[KGAUSS];
  float gs = 0.0f;
  for (int j = 0; j < KGAUSS; ++j) {
    float d = (float)(j - 12);
    float v = expf(-(d * d) * inv2s2);
    g[j] = v; gs += v;
  }
  float ginv = 1.0f / (gs + 1e-12f);
  for (int j = 0; j < KGAUSS; ++j) g[j] *= ginv;
  float aA  = log1pf(expf(pf[8448 + c])) + 1e-6f;
  float ab1 = log1pf(expf(pf[8961])) + 1e-6f;
  float ab2 = log1pf(expf(pf[8962])) + 1e-6f;
  __syncthreads();
  for (int i = t; i < L; i += 256) {
    float acc = 0.0f;
#pragma unroll
    for (int j = 0; j < KGAUSS; ++j) {
      int idx = i + j - 12;
      idx = idx < 0 ? -idx : (idx >= L ? 2 * L - 2 - idx : idx);
      acc += g[j] * xs[idx];
    }
    seasonal[(size_t)bc * L + i] = xs[i] - acc;
    if (b == 0) {
      float T = fminf(10.0f, fmaxf(-10.0f, acc));
      trend0[(size_t)c * L + i] = aA * (ab1 * log1pf(expf(ab2 * T)));
    }
  }
}

// -------- FUSED: radix-8 Hilbert phase + unwrap + corrector + I (L=8192) -----
// R8: 1024 threads, launch_bounds(1024, 4). R7's (1024,8) clamped the allocator
// to 32 VGPRs -> ~30 regs/thread spilled to scratch (WRITE_SIZE 21.5->64.5MB,
// FETCH 29->61MB) and time regressed. (1024,4) gives budget <=128; the kernel's
// natural footprint is ~56-64 (512-thread variant needed 64 with 2x the unwrap
// state). launch_bounds limits the ALLOCATOR, not HW residency: at <=64 VGPR the
// HW still schedules 2 blocks/CU (LDS 2x64KB) = 32 waves = 100% ceiling.
__global__ __launch_bounds__(1024, 4) void k_hilbert_unwrap(
    const float* __restrict__ sp, const float2* __restrict__ tw,
    const float* __restrict__ amp, const float* __restrict__ pf,
    bf16* __restrict__ I, int C, int L, int lg, long M) {
  __shared__ float2 z[LMAX];  // 64KB
  float* P = (float*)z;
  long r0 = 2L * blockIdx.x;
  int has1 = (r0 + 1 < M) ? 1 : 0;
  const float* row0 = sp + (size_t)r0 * L;
  const float* row1 = row0 + (has1 ? (size_t)L : 0);
  const int t = threadIdx.x;
  const int T = 1024;
  const int nq = L >> 3;

  // ---- forward triples: s = lg (global->LDS), then lg-3, ..., 4 ----
  for (int s = lg; s >= 4; s -= 3) {
    const int h4 = 1 << (s - 3);
    for (int q = t; q < nq; q += T) {
      int pos = q & (h4 - 1);
      int base = ((q >> (s - 3)) << s) + pos;
      float2 E0, E1, E2, E3, E4, E5, E6, E7;
      if (s == lg) {
        int i;
        i = base;          E0 = make_float2(row0[i], has1 ? row1[i] : 0.0f);
        i = base + h4;     E1 = make_float2(row0[i], has1 ? row1[i] : 0.0f);
        i = base + 2*h4;   E2 = make_float2(row0[i], has1 ? row1[i] : 0.0f);
        i = base + 3*h4;   E3 = make_float2(row0[i], has1 ? row1[i] : 0.0f);
        i = base + 4*h4;   E4 = make_float2(row0[i], has1 ? row1[i] : 0.0f);
        i = base + 5*h4;   E5 = make_float2(row0[i], has1 ? row1[i] : 0.0f);
        i = base + 6*h4;   E6 = make_float2(row0[i], has1 ? row1[i] : 0.0f);
        i = base + 7*h4;   E7 = make_float2(row0[i], has1 ? row1[i] : 0.0f);
      } else {
        E0 = z[ZI(base)];          E1 = z[ZI(base + h4)];
        E2 = z[ZI(base + 2*h4)];   E3 = z[ZI(base + 3*h4)];
        E4 = z[ZI(base + 4*h4)];   E5 = z[ZI(base + 5*h4)];
        E6 = z[ZI(base + 6*h4)];   E7 = z[ZI(base + 7*h4)];
      }
      float2 wa0 = tw[pos << (lg - s)];
      float2 wa1 = tw[(pos + h4) << (lg - s)];
      float2 wa2 = tw[(pos + 2*h4) << (lg - s)];
      float2 wa3 = tw[(pos + 3*h4) << (lg - s)];
      float2 wb0 = tw[pos << (lg - s + 1)];
      float2 wb1 = tw[(pos + h4) << (lg - s + 1)];
      float2 wc0 = tw[pos << (lg - s + 2)];
      float2 A0 = f2add(E0, E4), B0 = cmulc(f2sub(E0, E4), wa0);
      float2 A1 = f2add(E1, E5), B1 = cmulc(f2sub(E1, E5), wa1);
      float2 A2 = f2add(E2, E6), B2 = cmulc(f2sub(E2, E6), wa2);
      float2 A3 = f2add(E3, E7), B3 = cmulc(f2sub(E3, E7), wa3);
      float2 C0 = f2add(A0, A2), C2 = cmulc(f2sub(A0, A2), wb0);
      float2 C1 = f2add(A1, A3), C3 = cmulc(f2sub(A1, A3), wb1);
      float2 D0 = f2add(B0, B2), D2 = cmulc(f2sub(B0, B2), wb0);
      float2 D1 = f2add(B1, B3), D3 = cmulc(f2sub(B1, B3), wb1);
      z[ZI(base)]          = f2add(C0, C1);
      z[ZI(base + h4)]     = cmulc(f2sub(C0, C1), wc0);
      z[ZI(base + 2*h4)]   = f2add(C2, C3);
      z[ZI(base + 3*h4)]   = cmulc(f2sub(C2, C3), wc0);
      z[ZI(base + 4*h4)]   = f2add(D0, D1);
      z[ZI(base + 5*h4)]   = cmulc(f2sub(D0, D1), wc0);
      z[ZI(base + 6*h4)]   = f2add(D2, D3);
      z[ZI(base + 7*h4)]   = cmulc(f2sub(D2, D3), wc0);
    }
    __syncthreads();
  }
  // ---- middle: fwd s=1 + hilbert filter (+1/L) + inv s=1 ----
  {
    const float s1 = 1.0f / (float)L, s2 = 2.0f / (float)L;
    const int h = L >> 1;
    for (int q = t; q < (L >> 1); q += T) {
      int i0 = 2 * q, i1 = i0 + 1;
      float2 a = z[ZI(i0)], b = z[ZI(i1)];
      float2 u0 = f2add(a, b), u1 = f2sub(a, b);
      int k0 = (int)(__brev((unsigned)i0) >> (32 - lg));
      int k1 = (int)(__brev((unsigned)i1) >> (32 - lg));
      float sc0 = (k0 == 0 || k0 == h) ? s1 : (k0 < h ? s2 : 0.0f);
      float sc1 = (k1 == 0 || k1 == h) ? s1 : (k1 < h ? s2 : 0.0f);
      u0.x *= sc0; u0.y *= sc0; u1.x *= sc1; u1.y *= sc1;
      z[ZI(i0)] = f2add(u0, u1);
      z[ZI(i1)] = f2sub(u0, u1);
    }
  }
  __syncthreads();
  // ---- inverse triples s = 2, 5, ..., lg-5 (all but last) ----
  for (int s = 2; s + 2 <= lg - 3; s += 3) {
    const int h = 1 << (s - 1);
    for (int q = t; q < nq; q += T) {
      int pos = q & (h - 1);
      int base = ((q >> (s - 1)) << (s + 2)) + pos;
      float2 E0 = z[ZI(base)],         E1 = z[ZI(base + h)];
      float2 E2 = z[ZI(base + 2*h)],   E3 = z[ZI(base + 3*h)];
      float2 E4 = z[ZI(base + 4*h)],   E5 = z[ZI(base + 5*h)];
      float2 E6 = z[ZI(base + 6*h)],   E7 = z[ZI(base + 7*h)];
      float2 w0  = tw[pos << (lg - s)];
      float2 w10 = tw[pos << (lg - s - 1)];
      float2 w11 = tw[(pos + h) << (lg - s - 1)];
      float2 w20 = tw[pos << (lg - s - 2)];
      float2 w21 = tw[(pos + h) << (lg - s - 2)];
      float2 w22 = tw[(pos + 2*h) << (lg - s - 2)];
      float2 w23 = tw[(pos + 3*h) << (lg - s - 2)];
      float2 c;
      c = cmul(E1, w0); float2 A0 = f2add(E0, c), A1 = f2sub(E0, c);
      c = cmul(E3, w0); float2 A2 = f2add(E2, c), A3 = f2sub(E2, c);
      c = cmul(E5, w0); float2 A4 = f2add(E4, c), A5 = f2sub(E4, c);
      c = cmul(E7, w0); float2 A6 = f2add(E6, c), A7 = f2sub(E6, c);
      c = cmul(A2, w10); float2 B0 = f2add(A0, c), B2 = f2sub(A0, c);
      c = cmul(A3, w11); float2 B1 = f2add(A1, c), B3 = f2sub(A1, c);
      c = cmul(A6, w10); float2 B4 = f2add(A4, c), B6 = f2sub(A4, c);
      c = cmul(A7, w11); float2 B5 = f2add(A5, c), B7 = f2sub(A5, c);
      float2 F0, F1, F2, F3, F4, F5, F6, F7;
      c = cmul(B4, w20); F0 = f2add(B0, c); F4 = f2sub(B0, c);
      c = cmul(B5, w21); F1 = f2add(B1, c); F5 = f2sub(B1, c);
      c = cmul(B6, w22); F2 = f2add(B2, c); F6 = f2sub(B2, c);
      c = cmul(B7, w23); F3 = f2add(B3, c); F7 = f2sub(B3, c);
      z[ZI(base)]        = F0; z[ZI(base + h)]    = F1;
      z[ZI(base + 2*h)]  = F2; z[ZI(base + 3*h)]  = F3;
      z[ZI(base + 4*h)]  = F4; z[ZI(base + 5*h)]  = F5;
      z[ZI(base + 6*h)]  = F6; z[ZI(base + 7*h)]  = F7;
    }
    __syncthreads();
  }
  // ---- last inverse triple (s = lg-2): preload (single iteration at T=1024),
  //      barrier, then write atan2 phases into P (aliases z, XS layout) ----
  {
    const int s = lg - 2;
    const int h = 1 << (s - 1);
    float2 Ea[8];
    int q = t;
    int pos = q & (h - 1);
    int base = ((q >> (s - 1)) << (s + 2)) + pos;
    Ea[0] = z[ZI(base)];         Ea[1] = z[ZI(base + h)];
    Ea[2] = z[ZI(base + 2*h)];   Ea[3] = z[ZI(base + 3*h)];
    Ea[4] = z[ZI(base + 4*h)];   Ea[5] = z[ZI(base + 5*h)];
    Ea[6] = z[ZI(base + 6*h)];   Ea[7] = z[ZI(base + 7*h)];
    __syncthreads();  // all z reads complete before any P (alias) writes
    float2 w0  = tw[pos << (lg - s)];
    float2 w10 = tw[pos << (lg - s - 1)];
    float2 w11 = tw[(pos + h) << (lg - s - 1)];
    float2 w20 = tw[pos << (lg - s - 2)];
    float2 w21 = tw[(pos + h) << (lg - s - 2)];
    float2 w22 = tw[(pos + 2*h) << (lg - s - 2)];
    float2 w23 = tw[(pos + 3*h) << (lg - s - 2)];
    float2 c;
    c = cmul(Ea[1], w0); float2 A0 = f2add(Ea[0], c), A1 = f2sub(Ea[0], c);
    c = cmul(Ea[3], w0); float2 A2 = f2add(Ea[2], c), A3 = f2sub(Ea[2], c);
    c = cmul(Ea[5], w0); float2 A4 = f2add(Ea[4], c), A5 = f2sub(Ea[4], c);
    c = cmul(Ea[7], w0); float2 A6 = f2add(Ea[6], c), A7 = f2sub(Ea[6], c);
    c = cmul(A2, w10); float2 B0 = f2add(A0, c), B2 = f2sub(A0, c);
    c = cmul(A3, w11); float2 B1 = f2add(A1, c), B3 = f2sub(A1, c);
    c = cmul(A6, w10); float2 B4 = f2add(A4, c), B6 = f2sub(A4, c);
    c = cmul(A7, w11); float2 B5 = f2add(A5, c), B7 = f2sub(A5, c);
    float2 F[8];
    c = cmul(B4, w20); F[0] = f2add(B0, c); F[4] = f2sub(B0, c);
    c = cmul(B5, w21); F[1] = f2add(B1, c); F[5] = f2sub(B1, c);
    c = cmul(B6, w22); F[2] = f2add(B2, c); F[6] = f2sub(B2, c);
    c = cmul(B7, w23); F[3] = f2add(B3, c); F[7] = f2sub(B3, c);
#pragma unroll
    for (int j = 0; j < 8; ++j) {
      int i = base + j * h;
      float xa = row0[i];
      float xb = has1 ? row1[i] : 0.0f;
      float ha = F[j].y - xb;   // H(a)
      float hb = xa - F[j].x;   // H(b)
      P[XS(i)] = atan2f(ha, xa);
      P[L + XS(i)] = has1 ? atan2f(hb, xb) : 0.0f;
    }
  }
  __syncthreads();
  // ---- fused unwrap + corrector + I (16 elems/thread, 512 threads/row) ----
  {
    int tr = t & 511, row = t >> 9;
    int rowoff = row ? L : 0;
    int c = (int)((r0 + row) % C);
    int sb = 16 * tr;
    float v[16];
#pragma unroll
    for (int ii = 0; ii < 16; ++ii) v[ii] = P[rowoff + XS(sb + ii)];
    float prev0 = (tr > 0) ? P[rowoff + XS(sb - 1)] : 0.0f;
    __syncthreads();  // raw phase reads done; slots 0..15 borrowable for scan
    int run = 0;
    {
      float prev = prev0;
#pragma unroll
      for (int ii = 0; ii < 16; ++ii) {
        float cur = v[ii];
        if (ii > 0 || tr > 0) {
          float d = cur - prev;
          int k = (int)floorf((d + PI_F) * (1.0f / TWO_PI_F));
          float m = d - TWO_PI_F * (float)k;
          if (m == -PI_F && d > 0.0f) k -= 1;
          run -= k;
        }
        prev = cur;
        v[ii] = cur + TWO_PI_F * (float)run;
      }
    }
    int lane = t & 63, w = t >> 6;  // waves 0-7: row a, 8-15: row b
    int inc = run;
#pragma unroll
    for (int off2 = 1; off2 < 64; off2 <<= 1) {
      int n = __shfl_up(inc, off2);
      if (lane >= off2) inc += n;
    }
    int* iP = (int*)P;
    if (lane == 63) iP[w] = inc;   // borrowed slots 0..15 (raw phases dead)
    __syncthreads();
    int base = inc - run;          // exclusive within wave
    int rowbase = row * 8;
    for (int ww = rowbase; ww < w; ++ww) base += iP[ww];
    __syncthreads();               // scan-slot reads done before publish
    float fb = TWO_PI_F * (float)base;
#pragma unroll
    for (int ii = 0; ii < 16; ++ii) v[ii] += fb;
#pragma unroll
    for (int ii = 0; ii < 16; ++ii) P[rowoff + XS(sb + ii)] = v[ii];
    __syncthreads();
    float hl[7], hr[7];
#pragma unroll
    for (int m = 0; m < 7; ++m)    // pos 16tr-7+m ; tr==0 reflects to v[7-m]
      hl[m] = (tr == 0) ? v[7 - m] : P[rowoff + XS(sb - 7 + m)];
#pragma unroll
    for (int m = 0; m < 7; ++m)    // pos 16tr+16+m ; tr==511 reflects v[14-m]
      hr[m] = (tr == 511) ? v[14 - m] : P[rowoff + XS(sb + 16 + m)];
    __syncthreads();               // halo reads done before cos overwrites
    float wz[15];
    float mean = 0.0f;
#pragma unroll
    for (int j = 0; j < 15; ++j) { wz[j] = pf[4352 + c * 15 + j]; mean += wz[j]; }
    mean *= (1.0f / 15.0f);
#pragma unroll
    for (int j = 0; j < 15; ++j) wz[j] -= mean;
    float tanh_s = tanhf(pf[8960]);
    float phi0c = pf[8704 + c];
#pragma unroll
    for (int ii = 0; ii < 16; ++ii) {
      float delta = 0.0f;
#pragma unroll
      for (int j = 0; j < 15; ++j) {
        int idx = ii + j - 7;  // compile-time
        float u = (idx < 0) ? hl[idx + 7] : (idx >= 16 ? hr[idx - 16] : v[idx]);
        delta = fmaf(wz[j], u, delta);
      }
      float phi = v[ii] + tanh_s * delta + phi0c;
      P[rowoff + XS(sb + ii)] = cosf(phi);
    }
    __syncthreads();
    const float* ar0 = amp + (size_t)(r0 % C) * L;
    const float* ar1 = amp + (size_t)((r0 + 1) % C) * L;
    bf16* I0 = I + (size_t)r0 * L;
    bf16* I1 = I0 + L;
    for (int i = t; i < L; i += 1024) {
      I0[i] = f2b(ar0[i] * P[XS(i)]);
      if (has1) I1[i] = f2b(ar1[i] * P[L + XS(i)]);
    }
  }
}

// ---------------- Hilbert radix-8 standalone (fallback; writes phases) -------
__global__ __launch_bounds__(512, 4) void k_hilbert8(float* __restrict__ sp,
    const float2* __restrict__ tw, int L, int lg, long M) {
  __shared__ float2 z[LMAX];  // 64KB
  long r0 = 2L * blockIdx.x;
  int has1 = (r0 + 1 < M) ? 1 : 0;
  float* row0 = sp + (size_t)r0 * L;
  float* row1 = row0 + (has1 ? (size_t)L : 0);
  const int t = threadIdx.x;
  const int T = 512;
  const int nq = L >> 3;

  for (int s = lg; s >= 4; s -= 3) {
    const int h4 = 1 << (s - 3);
    for (int q = t; q < nq; q += T) {
      int pos = q & (h4 - 1);
      int base = ((q >> (s - 3)) << s) + pos;
      float2 E0, E1, E2, E3, E4, E5, E6, E7;
      if (s == lg) {
        int i;
        i = base;          E0 = make_float2(row0[i], has1 ? row1[i] : 0.0f);
        i = base + h4;     E1 = make_float2(row0[i], has1 ? row1[i] : 0.0f);
        i = base + 2*h4;   E2 = make_float2(row0[i], has1 ? row1[i] : 0.0f);
        i = base + 3*h4;   E3 = make_float2(row0[i], has1 ? row1[i] : 0.0f);
        i = base + 4*h4;   E4 = make_float2(row0[i], has1 ? row1[i] : 0.0f);
        i = base + 5*h4;   E5 = make_float2(row0[i], has1 ? row1[i] : 0.0f);
        i = base + 6*h4;   E6 = make_float2(row0[i], has1 ? row1[i] : 0.0f);
        i = base + 7*h4;   E7 = make_float2(row0[i], has1 ? row1[i] : 0.0f);
      } else {
        E0 = z[ZI(base)];          E1 = z[ZI(base + h4)];
        E2 = z[ZI(base + 2*h4)];   E3 = z[ZI(base + 3*h4)];
        E4 = z[ZI(base + 4*h4)];   E5 = z[ZI(base + 5*h4)];
        E6 = z[ZI(base + 6*h4)];   E7 = z[ZI(base + 7*h4)];
      }
      float2 wa0 = tw[pos << (lg - s)];
      float2 wa1 = tw[(pos + h4) << (lg - s)];
      float2 wa2 = tw[(pos + 2*h4) << (lg - s)];
      float2 wa3 = tw[(pos + 3*h4) << (lg - s)];
      float2 wb0 = tw[pos << (lg - s + 1)];
      float2 wb1 = tw[(pos + h4) << (lg - s + 1)];
      float2 wc0 = tw[pos << (lg - s + 2)];
      float2 A0 = f2add(E0, E4), B0 = cmulc(f2sub(E0, E4), wa0);
      float2 A1 = f2add(E1, E5), B1 = cmulc(f2sub(E1, E5), wa1);
      float2 A2 = f2add(E2, E6), B2 = cmulc(f2sub(E2, E6), wa2);
      float2 A3 = f2add(E3, E7), B3 = cmulc(f2sub(E3, E7), wa3);
      float2 C0 = f2add(A0, A2), C2 = cmulc(f2sub(A0, A2), wb0);
      float2 C1 = f2add(A1, A3), C3 = cmulc(f2sub(A1, A3), wb1);
      float2 D0 = f2add(B0, B2), D2 = cmulc(f2sub(B0, B2), wb0);
      float2 D1 = f2add(B1, B3), D3 = cmulc(f2sub(B1, B3), wb1);
      z[ZI(base)]          = f2add(C0, C1);
      z[ZI(base + h4)]     = cmulc(f2sub(C0, C1), wc0);
      z[ZI(base + 2*h4)]   = f2add(C2, C3);
      z[ZI(base + 3*h4)]   = cmulc(f2sub(C2, C3), wc0);
      z[ZI(base + 4*h4)]   = f2add(D0, D1);
      z[ZI(base + 5*h4)]   = cmulc(f2sub(D0, D1), wc0);
      z[ZI(base + 6*h4)]   = f2add(D2, D3);
      z[ZI(base + 7*h4)]   = cmulc(f2sub(D2, D3), wc0);
    }
    __syncthreads();
  }
  {
    const float s1 = 1.0f / (float)L, s2 = 2.0f / (float)L;
    const int h = L >> 1;
    for (int q = t; q < (L >> 1); q += T) {
      int i0 = 2 * q, i1 = i0 + 1;
      float2 a = z[ZI(i0)], b = z[ZI(i1)];
      float2 u0 = f2add(a, b), u1 = f2sub(a, b);
      int k0 = (int)(__brev((unsigned)i0) >> (32 - lg));
      int k1 = (int)(__brev((unsigned)i1) >> (32 - lg));
      float sc0 = (k0 == 0 || k0 == h) ? s1 : (k0 < h ? s2 : 0.0f);
      float sc1 = (k1 == 0 || k1 == h) ? s1 : (k1 < h ? s2 : 0.0f);
      u0.x *= sc0; u0.y *= sc0; u1.x *= sc1; u1.y *= sc1;
      z[ZI(i0)] = f2add(u0, u1);
      z[ZI(i1)] = f2sub(u0, u1);
    }
  }
  __syncthreads();
  for (int s = 2; s + 2 <= lg; s += 3) {
    const int h = 1 << (s - 1);
    const int last = (s + 2 == lg) ? 1 : 0;
    for (int q = t; q < nq; q += T) {
      int pos = q & (h - 1);
      int base = ((q >> (s - 1)) << (s + 2)) + pos;
      float2 E0 = z[ZI(base)],         E1 = z[ZI(base + h)];
      float2 E2 = z[ZI(base + 2*h)],   E3 = z[ZI(base + 3*h)];
      float2 E4 = z[ZI(base + 4*h)],   E5 = z[ZI(base + 5*h)];
      float2 E6 = z[ZI(base + 6*h)],   E7 = z[ZI(base + 7*h)];
      float2 w0  = tw[pos << (lg - s)];
      float2 w10 = tw[pos << (lg - s - 1)];
      float2 w11 = tw[(pos + h) << (lg - s - 1)];
      float2 w20 = tw[pos << (lg - s - 2)];
      float2 w21 = tw[(pos + h) << (lg - s - 2)];
      float2 w22 = tw[(pos + 2*h) << (lg - s - 2)];
      float2 w23 = tw[(pos + 3*h) << (lg - s - 2)];
      float2 c;
      c = cmul(E1, w0); float2 A0 = f2add(E0, c), A1 = f2sub(E0, c);
      c = cmul(E3, w0); float2 A2 = f2add(E2, c), A3 = f2sub(E2, c);
      c = cmul(E5, w0); float2 A4 = f2add(E4, c), A5 = f2sub(E4, c);
      c = cmul(E7, w0); float2 A6 = f2add(E6, c), A7 = f2sub(E6, c);
      c = cmul(A2, w10); float2 B0 = f2add(A0, c), B2 = f2sub(A0, c);
      c = cmul(A3, w11); float2 B1 = f2add(A1, c), B3 = f2sub(A1, c);
      c = cmul(A6, w10); float2 B4 = f2add(A4, c), B6 = f2sub(A4, c);
      c = cmul(A7, w11); float2 B5 = f2add(A5, c), B7 = f2sub(A5, c);
      float2 F0, F1, F2, F3, F4, F5, F6, F7;
      c = cmul(B4, w20); F0 = f2add(B0, c); F4 = f2sub(B0, c);
      c = cmul(B5, w21); F1 = f2add(B1, c); F5 = f2sub(B1, c);
      c = cmul(B6, w22); F2 = f2add(B2, c); F6 = f2sub(B2, c);
      c = cmul(B7, w23); F3 = f2add(B3, c); F7 = f2sub(B3, c);
      if (last) {
        float2 ov[8] = {F0, F1, F2, F3, F4, F5, F6, F7};
#pragma unroll
        for (int j = 0; j < 8; ++j) {
          int i = base + j * h;
          float xa = row0[i];
          float xb = has1 ? row1[i] : 0.0f;
          float ha = ov[j].y - xb;
          float hb = xa - ov[j].x;
          row0[i] = atan2f(ha, xa);
          if (has1) row1[i] = atan2f(hb, xb);
        }
      } else {
        z[ZI(base)]        = F0; z[ZI(base + h)]    = F1;
        z[ZI(base + 2*h)]  = F2; z[ZI(base + 3*h)]  = F3;
        z[ZI(base + 4*h)]  = F4; z[ZI(base + 5*h)]  = F5;
        z[ZI(base + 6*h)]  = F6; z[ZI(base + 7*h)]  = F7;
      }
    }
    if (!last) __syncthreads();
  }
}

// ---------------- Hilbert radix-4 fallback (any lg) --------------------------
__global__ __launch_bounds__(512, 4) void k_hilbert4(float* __restrict__ sp,
    const float2* __restrict__ tw, int L, int lg, long M) {
  __shared__ float2 z[LMAX];  // 64KB
  long r0 = 2L * blockIdx.x;
  int has1 = (r0 + 1 < M) ? 1 : 0;
  float* row0 = sp + (size_t)r0 * L;
  float* row1 = row0 + (has1 ? (size_t)L : 0);
  const int t = threadIdx.x;
  const int T = 512;
  const int nq = L >> 2;

  {
    const int s = lg;
    const int h = 1 << (s - 1), h2 = h >> 1;
    for (int q = t; q < nq; q += T) {
      int pos = q & (h2 - 1);
      int base = ((q >> (s - 2)) << s) + pos;
      int i0 = base, i1 = base + h2, i2 = base + h, i3 = base + h + h2;
      float2 e0 = make_float2(row0[i0], has1 ? row1[i0] : 0.0f);
      float2 e1 = make_float2(row0[i1], has1 ? row1[i1] : 0.0f);
      float2 e2 = make_float2(row0[i2], has1 ? row1[i2] : 0.0f);
      float2 e3 = make_float2(row0[i3], has1 ? row1[i3] : 0.0f);
      float2 wa = tw[pos << (lg - s)];
      float2 wb = tw[(pos + h2) << (lg - s)];
      float2 wc = tw[pos << (lg - s + 1)];
      float2 t0 = f2add(e0, e2), t2 = cmulc(f2sub(e0, e2), wa);
      float2 t1 = f2add(e1, e3), t3 = cmulc(f2sub(e1, e3), wb);
      z[ZI(i0)] = f2add(t0, t1);
      z[ZI(i1)] = cmulc(f2sub(t0, t1), wc);
      z[ZI(i2)] = f2add(t2, t3);
      z[ZI(i3)] = cmulc(f2sub(t2, t3), wc);
    }
  }
  __syncthreads();
  for (int s = lg - 2; s >= 2; s -= 2) {
    const int h = 1 << (s - 1), h2 = h >> 1;
    for (int q = t; q < nq; q += T) {
      int pos = q & (h2 - 1);
      int base = ((q >> (s - 2)) << s) + pos;
      int i0 = base, i1 = base + h2, i2 = base + h, i3 = base + h + h2;
      float2 e0 = z[ZI(i0)], e1 = z[ZI(i1)], e2 = z[ZI(i2)], e3 = z[ZI(i3)];
      float2 wa = tw[pos << (lg - s)];
      float2 wb = tw[(pos + h2) << (lg - s)];
      float2 wc = tw[pos << (lg - s + 1)];
      float2 t0 = f2add(e0, e2), t2 = cmulc(f2sub(e0, e2), wa);
      float2 t1 = f2add(e1, e3), t3 = cmulc(f2sub(e1, e3), wb);
      z[ZI(i0)] = f2add(t0, t1);
      z[ZI(i1)] = cmulc(f2sub(t0, t1), wc);
      z[ZI(i2)] = f2add(t2, t3);
      z[ZI(i3)] = cmulc(f2sub(t2, t3), wc);
    }
    __syncthreads();
  }
  {
    const float s1 = 1.0f / (float)L, s2 = 2.0f / (float)L;
    const int h = L >> 1;
    if (lg & 1) {
      for (int q = t; q < (L >> 1); q += T) {
        int i0 = 2 * q, i1 = i0 + 1;
        float2 a = z[ZI(i0)], b = z[ZI(i1)];
        float2 u0 = f2add(a, b), u1 = f2sub(a, b);
        int k0 = (int)(__brev((unsigned)i0) >> (32 - lg));
        int k1 = (int)(__brev((unsigned)i1) >> (32 - lg));
        float sc0 = (k0 == 0 || k0 == h) ? s1 : (k0 < h ? s2 : 0.0f);
        float sc1 = (k1 == 0 || k1 == h) ? s1 : (k1 < h ? s2 : 0.0f);
        u0.x *= sc0; u0.y *= sc0; u1.x *= sc1; u1.y *= sc1;
        z[ZI(i0)] = f2add(u0, u1);
        z[ZI(i1)] = f2sub(u0, u1);
      }
    } else {
      for (int p = t; p < L; p += T) {
        int k = (int)(__brev((unsigned)p) >> (32 - lg));
        float sc = (k == 0 || k == h) ? s1 : (k < h ? s2 : 0.0f);
        float2 v = z[ZI(p)];
        v.x *= sc; v.y *= sc;
        z[ZI(p)] = v;
      }
    }
  }
  __syncthreads();
  const int s0 = (lg & 1) ? 2 : 1;
  for (int s = s0; s + 1 <= lg - 2; s += 2) {
    const int hs = 1 << (s - 1);
    for (int q = t; q < nq; q += T) {
      int pos = q & (hs - 1);
      int base = ((q >> (s - 1)) << (s + 1)) + pos;
      int i0 = base, i1 = base + hs, i2 = base + 2 * hs, i3 = base + 3 * hs;
      float2 e0 = z[ZI(i0)], e1 = z[ZI(i1)], e2 = z[ZI(i2)], e3 = z[ZI(i3)];
      float2 wa = tw[pos << (lg - s)];
      float2 wb = tw[pos << (lg - s - 1)];
      float2 wcc = tw[(pos + hs) << (lg - s - 1)];
      float2 c1 = cmul(e1, wa);
      float2 t0 = f2add(e0, c1), t1 = f2sub(e0, c1);
      float2 d1 = cmul(e3, wa);
      float2 t2 = f2add(e2, d1), t3 = f2sub(e2, d1);
      c1 = cmul(t2, wb);
      float2 o0 = f2add(t0, c1), o2 = f2sub(t0, c1);
      d1 = cmul(t3, wcc);
      float2 o1 = f2add(t1, d1), o3 = f2sub(t1, d1);
      z[ZI(i0)] = o0; z[ZI(i1)] = o1; z[ZI(i2)] = o2; z[ZI(i3)] = o3;
    }
    __syncthreads();
  }
  {
    const int s = lg - 1;
    const int hs = 1 << (s - 1);
    for (int q = t; q < nq; q += T) {
      int pos = q & (hs - 1);
      int base = ((q >> (s - 1)) << (s + 1)) + pos;
      int i0 = base, i1 = base + hs, i2 = base + 2 * hs, i3 = base + 3 * hs;
      float2 e0 = z[ZI(i0)], e1 = z[ZI(i1)], e2 = z[ZI(i2)], e3 = z[ZI(i3)];
      float2 wa = tw[pos << (lg - s)];
      float2 wb = tw[pos << (lg - s - 1)];
      float2 wcc = tw[(pos + hs) << (lg - s - 1)];
      float2 c1 = cmul(e1, wa);
      float2 t0 = f2add(e0, c1), t1 = f2sub(e0, c1);
      float2 d1 = cmul(e3, wa);
      float2 t2 = f2add(e2, d1), t3 = f2sub(e2, d1);
      c1 = cmul(t2, wb);
      float2 o0 = f2add(t0, c1), o2 = f2sub(t0, c1);
      d1 = cmul(t3, wcc);
      float2 o1 = f2add(t1, d1), o3 = f2sub(t1, d1);
      int idx[4] = {i0, i1, i2, i3};
      float2 ov[4] = {o0, o1, o2, o3};
#pragma unroll
      for (int j = 0; j < 4; ++j) {
        int i = idx[j];
        float xa = row0[i];
        float xb = has1 ? row1[i] : 0.0f;
        float2 w = ov[j];
        float ha = w.y - xb;
        float hb = xa - w.x;
        row0[i] = atan2f(ha, xa);
        if (has1) row1[i] = atan2f(hb, xb);
      }
    }
  }
}

// ---------------- unwrap fast path standalone (fallback) ---------------------
__global__ __launch_bounds__(256, 4) void k_unwrap_I32(
    const float* __restrict__ phase_all, const float* __restrict__ amp,
    const float* __restrict__ pf, bf16* __restrict__ I, int C, int L) {
  __shared__ float p[LMAX + LMAX / 32];  // skewed
  __shared__ int wsum[8];
  int bc = blockIdx.x, c = bc % C;
  int t = threadIdx.x;
  const float* prow = phase_all + (size_t)bc * L;
  for (int i = t; i < L; i += 256) p[i + (i >> 5)] = prow[i];
  __syncthreads();
  const int sbase = 33 * t;  // si(32*t)
  float v[32];
#pragma unroll
  for (int ii = 0; ii < 32; ++ii) v[ii] = p[sbase + ii];
  float prev = (t > 0) ? p[sbase - 2] : 0.0f;  // si(32t-1)
  int run = 0;
#pragma unroll
  for (int ii = 0; ii < 32; ++ii) {
    float cur = v[ii];
    if (ii > 0 || t > 0) {
      float d = cur - prev;
      int k = (int)floorf((d + PI_F) * (1.0f / TWO_PI_F));
      float m = d - TWO_PI_F * (float)k;
      if (m == -PI_F && d > 0.0f) k -= 1;
      run -= k;
    }
    prev = cur;
    v[ii] = cur + TWO_PI_F * (float)run;
  }
  int lane = t & 63, w = t >> 6;
  int inc = run;
#pragma unroll
  for (int off = 1; off < 64; off <<= 1) {
    int n = __shfl_up(inc, off);
    if (lane >= off) inc += n;
  }
  if (lane == 63) wsum[w] = inc;
  __syncthreads();
  int base = inc - run;
  for (int ww = 0; ww < w; ++ww) base += wsum[ww];
  float fb = TWO_PI_F * (float)base;
#pragma unroll
  for (int ii = 0; ii < 32; ++ii) v[ii] += fb;
#pragma unroll
  for (int ii = 0; ii < 32; ++ii) p[sbase + ii] = v[ii];
  __syncthreads();
  float hl[7], hr[7];
#pragma unroll
  for (int m = 0; m < 7; ++m)
    hl[m] = (t == 0) ? v[7 - m] : p[sbase - 8 + m];
#pragma unroll
  for (int m = 0; m < 7; ++m)
    hr[m] = (t == 255) ? v[30 - m] : p[sbase + 33 + m];
  __syncthreads();
  float wz[15];
  float mean = 0.0f;
#pragma unroll
  for (int j = 0; j < 15; ++j) { wz[j] = pf[4352 + c * 15 + j]; mean += wz[j]; }
  mean /= 15.0f;
#pragma unroll
  for (int j = 0; j < 15; ++j) wz[j] -= mean;
  float tanh_s = tanhf(pf[8960]);
  float phi0c = pf[8704 + c];
#pragma unroll
  for (int ii = 0; ii < 32; ++ii) {
    float delta = 0.0f;
#pragma unroll
    for (int j = 0; j < 15; ++j) {
      int idx = ii + j - 7;
      float u = (idx < 0) ? hl[idx + 7] : (idx >= 32 ? hr[idx - 32] : v[idx]);
      delta = fmaf(wz[j], u, delta);
    }
    float phi = v[ii] + tanh_s * delta + phi0c;
    p[sbase + ii] = cosf(phi);
  }
  __syncthreads();
  const float* arow = amp + (size_t)c * L;
  bf16* Irow = I + (size_t)bc * L;
  for (int i = t; i < L; i += 256)
    Irow[i] = f2b(arow[i] * p[i + (i >> 5)]);
}

// ---------------- unwrap legacy path (generic L, KP) -------------------------
__global__ __launch_bounds__(256) void k_unwrap_I(const float* __restrict__ phase_all,
    const float* __restrict__ amp, const float* __restrict__ pf,
    bf16* __restrict__ I, int C, int L, int KP) {
  __shared__ float p[LMAX];
  __shared__ int ksum[256];
  int bc = blockIdx.x;
  int c = bc % C;
  int t = threadIdx.x;
  int chunk = L >> 8;
  const float* prow = phase_all + (size_t)bc * L;
  for (int i = t; i < L; i += 256) p[i] = prow[i];
  __syncthreads();
  int start = t * chunk;
  float prev0 = (t > 0) ? p[start - 1] : 0.0f;
  int kacc = 0;
  {
    float prev = prev0;
    for (int ii = 0; ii < chunk; ++ii) {
      int i = start + ii;
      float cur = p[i];
      if (i > 0) {
        float d = cur - prev;
        int k = (int)floorf((d + PI_F) * (1.0f / TWO_PI_F));
        float m = d - TWO_PI_F * (float)k;
        if (m == -PI_F && d > 0.0f) k -= 1;
        kacc -= k;
      }
      prev = cur;
    }
  }
  ksum[t] = kacc;
  __syncthreads();
  if (t == 0) {
    int run = 0;
    for (int i = 0; i < 256; ++i) { int v = ksum[i]; ksum[i] = run; run += v; }
  }
  __syncthreads();
  {
    int run = ksum[t];
    float prev = prev0;
    for (int ii = 0; ii < chunk; ++ii) {
      int i = start + ii;
      float cur = p[i];
      if (i > 0) {
        float d = cur - prev;
        int k = (int)floorf((d + PI_F) * (1.0f / TWO_PI_F));
        float m = d - TWO_PI_F * (float)k;
        if (m == -PI_F && d > 0.0f) k -= 1;
        run -= k;
      }
      prev = cur;
      p[i] = cur + TWO_PI_F * (float)run;
    }
  }
  __syncthreads();
  float wz[32];
  float mean = 0.0f;
  for (int j = 0; j < KP; ++j) { wz[j] = pf[4352 + c * KP + j]; mean += wz[j]; }
  mean /= (float)KP;
  for (int j = 0; j < KP; ++j) wz[j] -= mean;
  int hk = KP / 2;
  float tanh_s = tanhf(pf[8960]);
  float phi0c = pf[8704 + c];
  const float* arow = amp + (size_t)c * L;
  bf16* Irow = I + (size_t)bc * L;
  for (int i = t; i < L; i += 256) {
    float delta = 0.0f;
    for (int j = 0; j < KP; ++j) {
      int idx = i + j - hk;
      idx = idx < 0 ? -idx : (idx >= L ? 2 * L - 2 - idx : idx);
      delta = fmaf(wz[j], p[idx], delta);
    }
    float phi = p[i] + tanh_s * delta + phi0c;
    Irow[i] = f2b(arow[i] * cosf(phi));
  }
}

// -------- MFMA GEMM, fused pair + split-K, double-buffered 2-phase ----------
__global__ __launch_bounds__(256) void k_gemm_sk(const bf16* __restrict__ A0,
    const bf16* __restrict__ A1, const bf16* __restrict__ B0,
    const bf16* __restrict__ B1, float* __restrict__ part,
    int M, int L, int D, int KS, int KC) {
  __shared__ __align__(16) u16 As[2][128 * 32];
  __shared__ __align__(16) u16 Bs[2][128 * 32];
  int zz = blockIdx.z;
  int g = zz / KS, ks = zz - g * KS;
  const u16* Ag = (const u16*)(g ? A1 : A0);
  const u16* Bg = (const u16*)(g ? B1 : B0);
  int m0 = blockIdx.x * 128, n0 = blockIdx.y * 128;
  int t = threadIdx.x;
  int l = t & 63, w = t >> 6;
  int wm = (w >> 1) * 64, wn = (w & 1) * 64;
  int lr = l & 15, lq = l >> 4;
  f32x4 acc[4][4];
  f32x4 z4 = 0.0f;
  for (int i = 0; i < 4; ++i)
    for (int j = 0; j < 4; ++j) acc[i][j] = z4;

  int row = t >> 2, kc = t & 3;
  int ar = m0 + row; ar = ar < M ? ar : M - 1;
  int br = n0 + row; br = br < D ? br : D - 1;
  int row2 = (256 + t) >> 2, kc2 = t & 3;
  int ar2 = m0 + row2; ar2 = ar2 < M ? ar2 : M - 1;
  int br2 = n0 + row2; br2 = br2 < D ? br2 : D - 1;

  int kbeg = ks * KC, kend = kbeg + KC;
  auto STAGE = [&](int buf, int k0) {
    async16(Ag + (size_t)ar * L + (k0 + kc * 8), &As[buf][t * 8]);
    async16(Bg + (size_t)br * L + (k0 + kc * 8), &Bs[buf][t * 8]);
    async16(Ag + (size_t)ar2 * L + (k0 + kc2 * 8), &As[buf][(256 + t) * 8]);
    async16(Bg + (size_t)br2 * L + (k0 + kc2 * 8), &Bs[buf][(256 + t) * 8]);
  };
  STAGE(0, kbeg);
  int cur = 0;
  for (int k0 = kbeg; k0 < kend; k0 += 32) {
    __syncthreads();                       // buf[cur] staged; prior reads done
    if (k0 + 32 < kend) STAGE(cur ^ 1, k0 + 32);
    bf16x8 af[4], bfr[4];
#pragma unroll
    for (int i = 0; i < 4; ++i) {
      af[i]  = *(const bf16x8*)(&As[cur][(wm + i * 16 + lr) * 32 + lq * 8]);
      bfr[i] = *(const bf16x8*)(&Bs[cur][(wn + i * 16 + lr) * 32 + lq * 8]);
    }
#pragma unroll
    for (int i = 0; i < 4; ++i)
#pragma unroll
      for (int j = 0; j < 4; ++j)
        acc[i][j] = __builtin_amdgcn_mfma_f32_16x16x32_bf16(af[i], bfr[j], acc[i][j], 0, 0, 0);
    cur ^= 1;
  }
  float* pbase = part + (size_t)zz * M * D;
#pragma unroll
  for (int i = 0; i < 4; ++i) {
    int rowb = m0 + wm + i * 16 + lq * 4;
#pragma unroll
    for (int j = 0; j < 4; ++j) {
      int gcol = n0 + wn + j * 16 + lr;
      if (gcol < D) {
#pragma unroll
        for (int r = 0; r < 4; ++r) {
          int grow = rowb + r;
          if (grow < M)
            pbase[(size_t)grow * D + gcol] = acc[i][j][r];
        }
      }
    }
  }
}

// Vectorized reduce: float4 per thread over KS partials + bias + exact GELU.
__global__ __launch_bounds__(256) void k_reduce4(const float* __restrict__ part,
    const float* __restrict__ pf, float* __restrict__ out, long MD, int D, int KS) {
  long i4 = ((long)blockIdx.x * 256 + threadIdx.x) * 4;
  if (i4 >= 2 * MD) return;
  int g = (int)(i4 / MD);
  long r = i4 - (long)g * MD;
  const float* p = part + (size_t)g * KS * MD + r;
  float4 s = make_float4(0.f, 0.f, 0.f, 0.f);
  for (int ks = 0; ks < KS; ++ks) {
    float4 v = *(const float4*)(p + (size_t)ks * MD);
    s.x += v.x; s.y += v.y; s.z += v.z; s.w += v.w;
  }
  int d = (int)(r % (long)D);
  const float* bias = pf + g * 2048 + d;
  float vv[4] = {s.x, s.y, s.z, s.w};
  float4 o;
  float* po = (float*)&o;
#pragma unroll
  for (int j = 0; j < 4; ++j) {
    float v = vv[j] + bias[j];
    po[j] = 0.5f * v * (1.0f + erff(v * 0.70710678118654752f));
  }
  *(float4*)(out + i4) = o;
}

// Scalar fallback (D or MD not divisible by 4).
__global__ __launch_bounds__(256) void k_reduce(const float* __restrict__ part,
    const float* __restrict__ pf, float* __restrict__ out, long MD, int D, int KS) {
  long idx = (long)blockIdx.x * 256 + threadIdx.x;
  if (idx >= 2 * MD) return;
  int g = (int)(idx / MD);
  long r = idx - (long)g * MD;
  const float* p = part + (size_t)g * KS * MD + r;
  float s = 0.0f;
  for (int ks = 0; ks < KS; ++ks) s += p[(size_t)ks * MD];
  int d = (int)(r % (long)D);
  float v = s + pf[g * 2048 + d];
  out[idx] = 0.5f * v * (1.0f + erff(v * 0.70710678118654752f));
}

// ---------------- launcher ----------------
static inline int cdiv_i(long a, long b) { return (int)((a + b - 1) / b); }

extern "C" void kernel_launch(void* const* d_in, const int* in_sizes, int n_in,
                              void* d_out, int out_size, void* d_ws, size_t ws_size,
                              hipStream_t stream) {
  // Dict order: 0 x_input,1 x_w,2 x_b,3 i_w,4 i_b,5 log_sigma,6 pc_weight,
  // 7 pc_strength,8 alpha_log,9 phi0,10 b1,11 b2.  d_out is FLOAT32.
  long B = 64, C = 21, L = 8192, D = 512, KP = 15;
  if (n_in == 12) {
    long Sx = in_sizes[0], Sw = in_sizes[1], Sb = in_sizes[2];
    long Sls = in_sizes[5], Spw = in_sizes[6];
    if (Sb > 0 && Sw % Sb == 0 && Sls > 0 && Spw % Sls == 0) {
      long Lc = Sw / Sb, KPc = Spw / Sls;
      if (Lc >= 256 && Lc <= LMAX && !(Lc & (Lc - 1)) && (KPc & 1) && KPc <= 31 &&
          Sx % (Sls * Lc) == 0) {
        L = Lc; D = Sb; C = Sls; KP = KPc; B = Sx / (Sls * Lc);
      }
    }
  }
  long M = B * C;
  int lg = 0; while ((1L << lg) < L) ++lg;

  const void* x_input = d_in[0];
  const void* x_w     = d_in[1];
  const void* x_b     = d_in[2];
  const void* i_w     = d_in[3];
  const void* i_b     = d_in[4];
  const void* lsg     = d_in[5];
  const void* pw      = d_in[6];
  const void* ps      = d_in[7];
  const void* al      = d_in[8];
  const void* ph      = d_in[9];
  const void* b1      = d_in[10];
  const void* b2      = d_in[11];

  char* ws = (char*)d_ws;
  size_t off = 0;
  auto take = [&](size_t bytes) { size_t o = off; off = (off + bytes + 255) & ~(size_t)255; return o; };
  float*  seasonal = (float*)(ws + take((size_t)M * L * 4));
  float*  trend0   = (float*)(ws + take((size_t)C * L * 4));
  bf16*   Ibuf     = (bf16*)(ws + take((size_t)M * L * 2));
  float2* tw       = (float2*)(ws + take((size_t)(L / 2) * 8));
  float*  pf       = (float*)(ws + take(65536));
  int*    flag     = (int*)(ws + take(256));
  bf16*   Xb       = (bf16*)(ws + take((size_t)M * L * 2));
  bf16*   Btx      = (bf16*)(ws + take((size_t)D * L * 2));
  bf16*   Bti      = (bf16*)(ws + take((size_t)D * L * 2));
  if (ws_size < off) return;

  // split-K factor: largest pow2 <= 8 with K-chunks %32==0 and partials fitting
  // in the (dead-after-unwrap) seasonal buffer: 2*KS*D <= L.
  int KS = 8;
  while (KS > 1 && ((L % ((long)KS * 32)) != 0 || 2L * KS * D > L)) KS >>= 1;
  float* out0 = (float*)d_out;
  float* part = (2L * KS * D <= L) ? seasonal : out0;  // fallback: in-place, KS==1
  int KC = (int)(L / KS);

  k_params<<<64 + cdiv_i(L / 2, 256), 256, 0, stream>>>(
      x_b, i_b, lsg, pw, al, ph, ps, b1, b2, pf, flag, tw,
      (int)D, (int)C, (int)KP, (int)L);

  k_transpose2<<<dim3(cdiv_i(L, 64), cdiv_i(D, 64), 2), 256, 0, stream>>>(
      x_w, i_w, Btx, Bti, flag, (int)L, (int)D);

  if (L == 8192)
    k_decomp32<<<(int)M, 256, 0, stream>>>(x_input, flag, pf, seasonal, trend0, Xb,
                                           (int)C, (int)L);
  else
    k_decomp<<<(int)M, 256, 0, stream>>>(x_input, flag, pf, seasonal, trend0, Xb,
                                         (int)C, (int)L);

  bool fused = (L == 8192 && KP == 15 && ((lg - 1) % 3 == 0));
  if (fused) {
    k_hilbert_unwrap<<<cdiv_i(M, 2), 1024, 0, stream>>>(
        seasonal, tw, trend0, pf, Ibuf, (int)C, (int)L, lg, M);
  } else {
    if ((lg - 1) % 3 == 0)
      k_hilbert8<<<cdiv_i(M, 2), 512, 0, stream>>>(seasonal, tw, (int)L, lg, M);
    else
      k_hilbert4<<<cdiv_i(M, 2), 512, 0, stream>>>(seasonal, tw, (int)L, lg, M);
    if (L == 8192 && KP == 15)
      k_unwrap_I32<<<(int)M, 256, 0, stream>>>(seasonal, trend0, pf, Ibuf, (int)C, (int)L);
    else
      k_unwrap_I<<<(int)M, 256, 0, stream>>>(seasonal, trend0, pf, Ibuf, (int)C, (int)L,
                                             (int)KP);
  }

  k_gemm_sk<<<dim3(cdiv_i(M, 128), cdiv_i(D, 128), 2 * KS), 256, 0, stream>>>(
      Xb, Ibuf, Btx, Bti, part, (int)M, (int)L, (int)D, KS, KC);
  if ((D % 4 == 0) && ((M * D) % 4 == 0))
    k_reduce4<<<cdiv_i(2 * M * D / 4, 256), 256, 0, stream>>>(part, pf, out0, M * D,
                                                              (int)D, KS);
  else
    k_reduce<<<cdiv_i(2 * M * D, 256), 256, 0, stream>>>(part, pf, out0, M * D,
                                                         (int)D, KS);
}

// Round 10
// 335.391 us; speedup vs baseline: 1.0954x; 1.0954x over previous
//
#include <hip/hip_runtime.h>
#include <hip/hip_bf16.h>
#include <math.h>

// Static maxima (LDS sizing); actual dims derived at runtime from in_sizes.
#define LMAX 8192
#define KGAUSS 25

#define PI_F 3.14159265358979323846f
#define TWO_PI_F 6.28318530717958647692f

typedef __hip_bfloat16 bf16;
typedef unsigned short u16;
typedef short bf16x8 __attribute__((ext_vector_type(8)));
typedef float f32x4 __attribute__((ext_vector_type(4)));

__device__ __forceinline__ float b2f(bf16 v) { return __bfloat162float(v); }
__device__ __forceinline__ bf16 f2b(float v) { return __float2bfloat16(v); }
__device__ __forceinline__ float rdv(const void* p, long i, int isb) {
  return isb ? b2f(((const bf16*)p)[i]) : ((const float*)p)[i];
}

__device__ __forceinline__ void async16(const void* g, void* l) {
#if __has_builtin(__builtin_amdgcn_global_load_lds)
  __builtin_amdgcn_global_load_lds((const __attribute__((address_space(1))) void*)g,
                                   (__attribute__((address_space(3))) void*)l, 16, 0, 0);
#else
  *(uint4*)l = *(const uint4*)g;
#endif
}

// complex helpers for the FFT
__device__ __forceinline__ float2 f2add(float2 a, float2 b) {
  return make_float2(a.x + b.x, a.y + b.y);
}
__device__ __forceinline__ float2 f2sub(float2 a, float2 b) {
  return make_float2(a.x - b.x, a.y - b.y);
}
__device__ __forceinline__ float2 cmulc(float2 x, float2 w) {  // x * conj(w)
  return make_float2(x.x * w.x + x.y * w.y, x.y * w.x - x.x * w.y);
}
__device__ __forceinline__ float2 cmul(float2 x, float2 w) {   // x * w
  return make_float2(x.x * w.x - x.y * w.y, x.x * w.y + x.y * w.x);
}
// LDS bank swizzle for the complex FFT array (float2 index granularity).
#define ZI(i) ((i) ^ (((i) >> 4) & 15))
// LDS bank swizzle for float-array phase storage (float index granularity).
#define XS(i) ((i) ^ (((i) >> 5) & 31))

// ---------------- params + twiddle (detect inlined; one launch) -------------
// Small params -> f32 workspace, FIXED slots:
// xb@0, ib@2048, ls@4096, pw@4352, al@8448, ph@8704, ps@8960, b1@8961, b2@8962
__global__ void k_params(const void* xb, const void* ib, const void* ls, const void* pw,
                         const void* al, const void* ph, const void* ps, const void* b1,
                         const void* b2, float* pf, int* flag, float2* tw,
                         int D, int C, int KP, int L) {
  unsigned wls = ((const unsigned*)ls)[0];
  int isb = ((wls >> 16) == (wls & 0xffffu)) ? 1 : 0;
  int blk = blockIdx.x, t = threadIdx.x;
  if (blk < 64) {
    int i = blk * 256 + t;
    if (i == 0) flag[0] = isb;
    float v = 0.0f;
    if (i < D)                              v = rdv(xb, i, isb);
    else if (i >= 2048 && i < 2048 + D)     v = rdv(ib, i - 2048, isb);
    else if (i >= 4096 && i < 4096 + C)     v = rdv(ls, i - 4096, isb);
    else if (i >= 4352 && i < 4352 + C*KP)  v = rdv(pw, i - 4352, isb);
    else if (i >= 8448 && i < 8448 + C)     v = rdv(al, i - 8448, isb);
    else if (i >= 8704 && i < 8704 + C)     v = rdv(ph, i - 8704, isb);
    else if (i == 8960)                     v = rdv(ps, 0, isb);
    else if (i == 8961)                     v = rdv(b1, 0, isb);
    else if (i == 8962)                     v = rdv(b2, 0, isb);
    pf[i] = v;
  } else {
    int j = (blk - 64) * 256 + t;
    if (j < L / 2) {
      double a = 6.283185307179586476925286766559 * (double)j / (double)L;
      tw[j] = make_float2((float)cos(a), (float)sin(a));
    }
  }
}

// -------- transpose W[K][N] -> Wt[N][K] bf16, both weights in one launch -----
__global__ __launch_bounds__(256) void k_transpose2(const void* __restrict__ in0,
    const void* __restrict__ in1, bf16* __restrict__ out0, bf16* __restrict__ out1,
    const int* __restrict__ flag, int K, int N) {
  __shared__ u16 tile[64][65];
  int isb = *flag;
  const void* in = blockIdx.z ? in1 : in0;
  bf16* out = blockIdx.z ? out1 : out0;
  int r0 = blockIdx.x * 64, c0 = blockIdx.y * 64;
  int t = threadIdx.x;
#pragma unroll
  for (int i = 0; i < 16; ++i) {
    int idx = t + i * 256;
    int r = idx >> 6, cc = idx & 63;
    int gr = r0 + r; gr = gr < K ? gr : K - 1;
    int gc = c0 + cc; gc = gc < N ? gc : N - 1;
    size_t gi = (size_t)gr * N + gc;
    u16 v;
    if (isb) v = ((const u16*)in)[gi];
    else { bf16 h = f2b(((const float*)in)[gi]); v = *(u16*)&h; }
    tile[r][cc] = v;
  }
  __syncthreads();
#pragma unroll
  for (int i = 0; i < 16; ++i) {
    int idx = t + i * 256;
    int a = idx >> 6, bb = idx & 63;
    if (c0 + a < N && r0 + bb < K)
      ((u16*)out)[(size_t)(c0 + a) * K + (r0 + bb)] = tile[bb][a];
  }
}

// ------------- gaussian trend/seasonal, register sliding-window fast path ----
__global__ __launch_bounds__(256, 4) void k_decomp32(const void* __restrict__ x,
    const int* __restrict__ flag, const float* __restrict__ pf,
    float* __restrict__ seasonal, float* __restrict__ trend0,
    bf16* __restrict__ Xb, int C, int L) {
  __shared__ float xs[LMAX + LMAX / 32];  // skewed: si(i) = i + (i>>5)
  int bc = blockIdx.x, c = bc % C, b = bc / C;
  int t = threadIdx.x;
  int isb = *flag;
  for (int i = t; i < L; i += 256) {
    float xv = rdv(x, (size_t)bc * L + i, isb);
    xs[i + (i >> 5)] = xv;
    Xb[(size_t)bc * L + i] = f2b(xv);  // bf16 copy for the GEMM A-operand
  }
  float sigma = expf(pf[4096 + c]) + 1e-6f;
  float inv2s2 = 1.0f / (2.0f * sigma * sigma);
  float g[KGAUSS];
  float gs = 0.0f;
#pragma unroll
  for (int j = 0; j < KGAUSS; ++j) {
    float d = (float)(j - 12);
    float vv = expf(-(d * d) * inv2s2);
    g[j] = vv; gs += vv;
  }
  float ginv = 1.0f / (gs + 1e-12f);
#pragma unroll
  for (int j = 0; j < KGAUSS; ++j) g[j] *= ginv;
  __syncthreads();
  const int base = 32 * t;
  float v[56];  // x[base-12 .. base+43], reflect at row ends
#pragma unroll
  for (int m = 0; m < 56; ++m) {
    int idx = base + m - 12;
    idx = idx < 0 ? -idx : (idx >= L ? 2 * L - 2 - idx : idx);
    v[m] = xs[idx + (idx >> 5)];
  }
  __syncthreads();  // all xs reads done; reuse xs for seasonal
  const int sb = 33 * t;
  float aA = 0.0f, ab1 = 0.0f, ab2 = 0.0f;
  if (b == 0) {
    aA  = log1pf(expf(pf[8448 + c])) + 1e-6f;
    ab1 = log1pf(expf(pf[8961])) + 1e-6f;
    ab2 = log1pf(expf(pf[8962])) + 1e-6f;
  }
  float* trow = trend0 + (size_t)c * L;
#pragma unroll
  for (int ii = 0; ii < 32; ++ii) {
    float acc = 0.0f;
#pragma unroll
    for (int j = 0; j < KGAUSS; ++j) acc = fmaf(g[j], v[ii + j], acc);
    xs[sb + ii] = v[ii + 12] - acc;  // seasonal -> LDS
    if (b == 0) {
      float T = fminf(10.0f, fmaxf(-10.0f, acc));
      trow[base + ii] = aA * (ab1 * log1pf(expf(ab2 * T)));  // amp folded in
    }
  }
  __syncthreads();
  for (int i = t; i < L; i += 256)
    seasonal[(size_t)bc * L + i] = xs[i + (i >> 5)];
}

// ---------------- generic decomp fallback (amp folded in) --------------------
__global__ __launch_bounds__(256) void k_decomp(const void* __restrict__ x,
    const int* __restrict__ flag, const float* __restrict__ pf,
    float* __restrict__ seasonal, float* __restrict__ trend0,
    bf16* __restrict__ Xb, int C, int L) {
  __shared__ float xs[LMAX];
  int bc = blockIdx.x;
  int c = bc % C, b = bc / C;
  int t = threadIdx.x;
  int isb = *flag;
  for (int i = t; i < L; i += 256) {
    float xv = rdv(x, (size_t)bc * L + i, isb);
    xs[i] = xv;
    Xb[(size_t)bc * L + i] = f2b(xv);
  }
  float sigma = expf(pf[4096 + c]) + 1e-6f;
  float inv2s2 = 1.0f / (2.0f * sigma * sigma);
  float g[KGAUSS];
  float gs = 0.0f;
  for (int j = 0; j < KGAUSS; ++j) {
    float d = (float)(j - 12);
    float v = expf(-(d * d) * inv2s2);
    g[j] = v; gs += v;
  }
  float ginv = 1.0f / (gs + 1e-12f);
  for (int j = 0; j < KGAUSS; ++j) g[j] *= ginv;
  float aA  = log1pf(expf(pf[8448 + c])) + 1e-6f;
  float ab1 = log1pf(expf(pf[8961])) + 1e-6f;
  float ab2 = log1pf(expf(pf[8962])) + 1e-6f;
  __syncthreads();
  for (int i = t; i < L; i += 256) {
    float acc = 0.0f;
#pragma unroll
    for (int j = 0; j < KGAUSS; ++j) {
      int idx = i + j - 12;
      idx = idx < 0 ? -idx : (idx >= L ? 2 * L - 2 - idx : idx);
      acc += g[j] * xs[idx];
    }
    seasonal[(size_t)bc * L + i] = xs[i] - acc;
    if (b == 0) {
      float T = fminf(10.0f, fmaxf(-10.0f, acc));
      trend0[(size_t)c * L + i] = aA * (ab1 * log1pf(expf(ab2 * T)));
    }
  }
}

// -------- FUSED: radix-8 Hilbert phase + unwrap + corrector + I (L=8192) -----
// R9: REVERTED to the verified 512-thread R6/R7 form (114.5 us, passed twice).
// Both 1024-thread variants lost: (1024,8) spilled ~30 regs/thread to scratch;
// (1024,4) had no spills but each FFT phase dropped to 1 butterfly-group/thread
// (half the per-wave ILP per barrier interval) and all 16 waves converge on the
// same barrier -> 128 us. Occupancy path closed; 512 threads x 2 groups/phase
// is this kernel's operating point.
__global__ __launch_bounds__(512, 4) void k_hilbert_unwrap(
    const float* __restrict__ sp, const float2* __restrict__ tw,
    const float* __restrict__ amp, const float* __restrict__ pf,
    bf16* __restrict__ I, int C, int L, int lg, long M) {
  __shared__ float2 z[LMAX];  // 64KB
  float* P = (float*)z;
  long r0 = 2L * blockIdx.x;
  int has1 = (r0 + 1 < M) ? 1 : 0;
  const float* row0 = sp + (size_t)r0 * L;
  const float* row1 = row0 + (has1 ? (size_t)L : 0);
  const int t = threadIdx.x;
  const int T = 512;
  const int nq = L >> 3;

  // ---- forward triples: s = lg (global->LDS), then lg-3, ..., 4 ----
  for (int s = lg; s >= 4; s -= 3) {
    const int h4 = 1 << (s - 3);
    for (int q = t; q < nq; q += T) {
      int pos = q & (h4 - 1);
      int base = ((q >> (s - 3)) << s) + pos;
      float2 E0, E1, E2, E3, E4, E5, E6, E7;
      if (s == lg) {
        int i;
        i = base;          E0 = make_float2(row0[i], has1 ? row1[i] : 0.0f);
        i = base + h4;     E1 = make_float2(row0[i], has1 ? row1[i] : 0.0f);
        i = base + 2*h4;   E2 = make_float2(row0[i], has1 ? row1[i] : 0.0f);
        i = base + 3*h4;   E3 = make_float2(row0[i], has1 ? row1[i] : 0.0f);
        i = base + 4*h4;   E4 = make_float2(row0[i], has1 ? row1[i] : 0.0f);
        i = base + 5*h4;   E5 = make_float2(row0[i], has1 ? row1[i] : 0.0f);
        i = base + 6*h4;   E6 = make_float2(row0[i], has1 ? row1[i] : 0.0f);
        i = base + 7*h4;   E7 = make_float2(row0[i], has1 ? row1[i] : 0.0f);
      } else {
        E0 = z[ZI(base)];          E1 = z[ZI(base + h4)];
        E2 = z[ZI(base + 2*h4)];   E3 = z[ZI(base + 3*h4)];
        E4 = z[ZI(base + 4*h4)];   E5 = z[ZI(base + 5*h4)];
        E6 = z[ZI(base + 6*h4)];   E7 = z[ZI(base + 7*h4)];
      }
      float2 wa0 = tw[pos << (lg - s)];
      float2 wa1 = tw[(pos + h4) << (lg - s)];
      float2 wa2 = tw[(pos + 2*h4) << (lg - s)];
      float2 wa3 = tw[(pos + 3*h4) << (lg - s)];
      float2 wb0 = tw[pos << (lg - s + 1)];
      float2 wb1 = tw[(pos + h4) << (lg - s + 1)];
      float2 wc0 = tw[pos << (lg - s + 2)];
      float2 A0 = f2add(E0, E4), B0 = cmulc(f2sub(E0, E4), wa0);
      float2 A1 = f2add(E1, E5), B1 = cmulc(f2sub(E1, E5), wa1);
      float2 A2 = f2add(E2, E6), B2 = cmulc(f2sub(E2, E6), wa2);
      float2 A3 = f2add(E3, E7), B3 = cmulc(f2sub(E3, E7), wa3);
      float2 C0 = f2add(A0, A2), C2 = cmulc(f2sub(A0, A2), wb0);
      float2 C1 = f2add(A1, A3), C3 = cmulc(f2sub(A1, A3), wb1);
      float2 D0 = f2add(B0, B2), D2 = cmulc(f2sub(B0, B2), wb0);
      float2 D1 = f2add(B1, B3), D3 = cmulc(f2sub(B1, B3), wb1);
      z[ZI(base)]          = f2add(C0, C1);
      z[ZI(base + h4)]     = cmulc(f2sub(C0, C1), wc0);
      z[ZI(base + 2*h4)]   = f2add(C2, C3);
      z[ZI(base + 3*h4)]   = cmulc(f2sub(C2, C3), wc0);
      z[ZI(base + 4*h4)]   = f2add(D0, D1);
      z[ZI(base + 5*h4)]   = cmulc(f2sub(D0, D1), wc0);
      z[ZI(base + 6*h4)]   = f2add(D2, D3);
      z[ZI(base + 7*h4)]   = cmulc(f2sub(D2, D3), wc0);
    }
    __syncthreads();
  }
  // ---- middle: fwd s=1 + hilbert filter (+1/L) + inv s=1 ----
  {
    const float s1 = 1.0f / (float)L, s2 = 2.0f / (float)L;
    const int h = L >> 1;
    for (int q = t; q < (L >> 1); q += T) {
      int i0 = 2 * q, i1 = i0 + 1;
      float2 a = z[ZI(i0)], b = z[ZI(i1)];
      float2 u0 = f2add(a, b), u1 = f2sub(a, b);
      int k0 = (int)(__brev((unsigned)i0) >> (32 - lg));
      int k1 = (int)(__brev((unsigned)i1) >> (32 - lg));
      float sc0 = (k0 == 0 || k0 == h) ? s1 : (k0 < h ? s2 : 0.0f);
      float sc1 = (k1 == 0 || k1 == h) ? s1 : (k1 < h ? s2 : 0.0f);
      u0.x *= sc0; u0.y *= sc0; u1.x *= sc1; u1.y *= sc1;
      z[ZI(i0)] = f2add(u0, u1);
      z[ZI(i1)] = f2sub(u0, u1);
    }
  }
  __syncthreads();
  // ---- inverse triples s = 2, 5 (all but last) ----
  for (int s = 2; s + 2 <= lg - 3; s += 3) {
    const int h = 1 << (s - 1);
    for (int q = t; q < nq; q += T) {
      int pos = q & (h - 1);
      int base = ((q >> (s - 1)) << (s + 2)) + pos;
      float2 E0 = z[ZI(base)],         E1 = z[ZI(base + h)];
      float2 E2 = z[ZI(base + 2*h)],   E3 = z[ZI(base + 3*h)];
      float2 E4 = z[ZI(base + 4*h)],   E5 = z[ZI(base + 5*h)];
      float2 E6 = z[ZI(base + 6*h)],   E7 = z[ZI(base + 7*h)];
      float2 w0  = tw[pos << (lg - s)];
      float2 w10 = tw[pos << (lg - s - 1)];
      float2 w11 = tw[(pos + h) << (lg - s - 1)];
      float2 w20 = tw[pos << (lg - s - 2)];
      float2 w21 = tw[(pos + h) << (lg - s - 2)];
      float2 w22 = tw[(pos + 2*h) << (lg - s - 2)];
      float2 w23 = tw[(pos + 3*h) << (lg - s - 2)];
      float2 c;
      c = cmul(E1, w0); float2 A0 = f2add(E0, c), A1 = f2sub(E0, c);
      c = cmul(E3, w0); float2 A2 = f2add(E2, c), A3 = f2sub(E2, c);
      c = cmul(E5, w0); float2 A4 = f2add(E4, c), A5 = f2sub(E4, c);
      c = cmul(E7, w0); float2 A6 = f2add(E6, c), A7 = f2sub(E6, c);
      c = cmul(A2, w10); float2 B0 = f2add(A0, c), B2 = f2sub(A0, c);
      c = cmul(A3, w11); float2 B1 = f2add(A1, c), B3 = f2sub(A1, c);
      c = cmul(A6, w10); float2 B4 = f2add(A4, c), B6 = f2sub(A4, c);
      c = cmul(A7, w11); float2 B5 = f2add(A5, c), B7 = f2sub(A5, c);
      float2 F0, F1, F2, F3, F4, F5, F6, F7;
      c = cmul(B4, w20); F0 = f2add(B0, c); F4 = f2sub(B0, c);
      c = cmul(B5, w21); F1 = f2add(B1, c); F5 = f2sub(B1, c);
      c = cmul(B6, w22); F2 = f2add(B2, c); F6 = f2sub(B2, c);
      c = cmul(B7, w23); F3 = f2add(B3, c); F7 = f2sub(B3, c);
      z[ZI(base)]        = F0; z[ZI(base + h)]    = F1;
      z[ZI(base + 2*h)]  = F2; z[ZI(base + 3*h)]  = F3;
      z[ZI(base + 4*h)]  = F4; z[ZI(base + 5*h)]  = F5;
      z[ZI(base + 6*h)]  = F6; z[ZI(base + 7*h)]  = F7;
    }
    __syncthreads();
  }
  // ---- last inverse triple (s = lg-2): preload, barrier, write atan2 to P ----
  {
    const int s = lg - 2;
    const int h = 1 << (s - 1);
    float2 Ea[2][8];
    int bs[2];
#pragma unroll
    for (int it = 0; it < 2; ++it) {
      int q = t + it * T;
      int pos = q & (h - 1);
      int base = ((q >> (s - 1)) << (s + 2)) + pos;
      bs[it] = base;
      Ea[it][0] = z[ZI(base)];         Ea[it][1] = z[ZI(base + h)];
      Ea[it][2] = z[ZI(base + 2*h)];   Ea[it][3] = z[ZI(base + 3*h)];
      Ea[it][4] = z[ZI(base + 4*h)];   Ea[it][5] = z[ZI(base + 5*h)];
      Ea[it][6] = z[ZI(base + 6*h)];   Ea[it][7] = z[ZI(base + 7*h)];
    }
    __syncthreads();  // all z reads complete before any P (alias) writes
#pragma unroll
    for (int it = 0; it < 2; ++it) {
      int q = t + it * T;
      int pos = q & (h - 1);
      int base = bs[it];
      float2 w0  = tw[pos << (lg - s)];
      float2 w10 = tw[pos << (lg - s - 1)];
      float2 w11 = tw[(pos + h) << (lg - s - 1)];
      float2 w20 = tw[pos << (lg - s - 2)];
      float2 w21 = tw[(pos + h) << (lg - s - 2)];
      float2 w22 = tw[(pos + 2*h) << (lg - s - 2)];
      float2 w23 = tw[(pos + 3*h) << (lg - s - 2)];
      float2 c;
      c = cmul(Ea[it][1], w0); float2 A0 = f2add(Ea[it][0], c), A1 = f2sub(Ea[it][0], c);
      c = cmul(Ea[it][3], w0); float2 A2 = f2add(Ea[it][2], c), A3 = f2sub(Ea[it][2], c);
      c = cmul(Ea[it][5], w0); float2 A4 = f2add(Ea[it][4], c), A5 = f2sub(Ea[it][4], c);
      c = cmul(Ea[it][7], w0); float2 A6 = f2add(Ea[it][6], c), A7 = f2sub(Ea[it][6], c);
      c = cmul(A2, w10); float2 B0 = f2add(A0, c), B2 = f2sub(A0, c);
      c = cmul(A3, w11); float2 B1 = f2add(A1, c), B3 = f2sub(A1, c);
      c = cmul(A6, w10); float2 B4 = f2add(A4, c), B6 = f2sub(A4, c);
      c = cmul(A7, w11); float2 B5 = f2add(A5, c), B7 = f2sub(A5, c);
      float2 F[8];
      c = cmul(B4, w20); F[0] = f2add(B0, c); F[4] = f2sub(B0, c);
      c = cmul(B5, w21); F[1] = f2add(B1, c); F[5] = f2sub(B1, c);
      c = cmul(B6, w22); F[2] = f2add(B2, c); F[6] = f2sub(B2, c);
      c = cmul(B7, w23); F[3] = f2add(B3, c); F[7] = f2sub(B3, c);
#pragma unroll
      for (int j = 0; j < 8; ++j) {
        int i = base + j * h;
        float xa = row0[i];
        float xb = has1 ? row1[i] : 0.0f;
        float ha = F[j].y - xb;   // H(a)
        float hb = xa - F[j].x;   // H(b)
        P[XS(i)] = atan2f(ha, xa);
        P[L + XS(i)] = has1 ? atan2f(hb, xb) : 0.0f;
      }
    }
  }
  __syncthreads();
  // ---- fused unwrap + corrector + I ----
  {
    int tr = t & 255, row = t >> 8;
    int rowoff = row ? L : 0;
    int c = (int)((r0 + row) % C);
    int sb32 = 32 * tr;
    float v[32];
#pragma unroll
    for (int ii = 0; ii < 32; ++ii) v[ii] = P[rowoff + XS(sb32 + ii)];
    float prev0 = (tr > 0) ? P[rowoff + XS(sb32 - 1)] : 0.0f;
    __syncthreads();  // raw phase reads done; slots 0..7 borrowable for scan
    int run = 0;
    {
      float prev = prev0;
#pragma unroll
      for (int ii = 0; ii < 32; ++ii) {
        float cur = v[ii];
        if (ii > 0 || tr > 0) {
          float d = cur - prev;
          int k = (int)floorf((d + PI_F) * (1.0f / TWO_PI_F));
          float m = d - TWO_PI_F * (float)k;
          if (m == -PI_F && d > 0.0f) k -= 1;
          run -= k;
        }
        prev = cur;
        v[ii] = cur + TWO_PI_F * (float)run;
      }
    }
    int lane = t & 63, w = t >> 6;  // waves 0-3: row a, 4-7: row b
    int inc = run;
#pragma unroll
    for (int off2 = 1; off2 < 64; off2 <<= 1) {
      int n = __shfl_up(inc, off2);
      if (lane >= off2) inc += n;
    }
    int* iP = (int*)P;
    if (lane == 63) iP[w] = inc;   // borrowed slot (raw phases dead here)
    __syncthreads();
    int base = inc - run;          // exclusive within wave
    int rowbase = row * 4;
    for (int ww = rowbase; ww < w; ++ww) base += iP[ww];
    __syncthreads();               // scan-slot reads done before publish
    float fb = TWO_PI_F * (float)base;
#pragma unroll
    for (int ii = 0; ii < 32; ++ii) v[ii] += fb;
#pragma unroll
    for (int ii = 0; ii < 32; ++ii) P[rowoff + XS(sb32 + ii)] = v[ii];
    __syncthreads();
    float hl[7], hr[7];
#pragma unroll
    for (int m = 0; m < 7; ++m)
      hl[m] = (tr == 0) ? v[7 - m] : P[rowoff + XS(sb32 - 7 + m)];
#pragma unroll
    for (int m = 0; m < 7; ++m)
      hr[m] = (tr == 255) ? v[30 - m] : P[rowoff + XS(sb32 + 32 + m)];
    __syncthreads();               // halo reads done before cos overwrites
    float wz[15];
    float mean = 0.0f;
#pragma unroll
    for (int j = 0; j < 15; ++j) { wz[j] = pf[4352 + c * 15 + j]; mean += wz[j]; }
    mean *= (1.0f / 15.0f);
#pragma unroll
    for (int j = 0; j < 15; ++j) wz[j] -= mean;
    float tanh_s = tanhf(pf[8960]);
    float phi0c = pf[8704 + c];
#pragma unroll
    for (int ii = 0; ii < 32; ++ii) {
      float delta = 0.0f;
#pragma unroll
      for (int j = 0; j < 15; ++j) {
        int idx = ii + j - 7;
        float u = (idx < 0) ? hl[idx + 7] : (idx >= 32 ? hr[idx - 32] : v[idx]);
        delta = fmaf(wz[j], u, delta);
      }
      float phi = v[ii] + tanh_s * delta + phi0c;
      P[rowoff + XS(sb32 + ii)] = cosf(phi);
    }
    __syncthreads();
    const float* ar0 = amp + (size_t)(r0 % C) * L;
    const float* ar1 = amp + (size_t)((r0 + 1) % C) * L;
    bf16* I0 = I + (size_t)r0 * L;
    bf16* I1 = I0 + L;
    for (int i = t; i < L; i += 512) {
      I0[i] = f2b(ar0[i] * P[XS(i)]);
      if (has1) I1[i] = f2b(ar1[i] * P[L + XS(i)]);
    }
  }
}

// ---------------- Hilbert radix-8 standalone (fallback; writes phases) -------
__global__ __launch_bounds__(512, 4) void k_hilbert8(float* __restrict__ sp,
    const float2* __restrict__ tw, int L, int lg, long M) {
  __shared__ float2 z[LMAX];  // 64KB
  long r0 = 2L * blockIdx.x;
  int has1 = (r0 + 1 < M) ? 1 : 0;
  float* row0 = sp + (size_t)r0 * L;
  float* row1 = row0 + (has1 ? (size_t)L : 0);
  const int t = threadIdx.x;
  const int T = 512;
  const int nq = L >> 3;

  for (int s = lg; s >= 4; s -= 3) {
    const int h4 = 1 << (s - 3);
    for (int q = t; q < nq; q += T) {
      int pos = q & (h4 - 1);
      int base = ((q >> (s - 3)) << s) + pos;
      float2 E0, E1, E2, E3, E4, E5, E6, E7;
      if (s == lg) {
        int i;
        i = base;          E0 = make_float2(row0[i], has1 ? row1[i] : 0.0f);
        i = base + h4;     E1 = make_float2(row0[i], has1 ? row1[i] : 0.0f);
        i = base + 2*h4;   E2 = make_float2(row0[i], has1 ? row1[i] : 0.0f);
        i = base + 3*h4;   E3 = make_float2(row0[i], has1 ? row1[i] : 0.0f);
        i = base + 4*h4;   E4 = make_float2(row0[i], has1 ? row1[i] : 0.0f);
        i = base + 5*h4;   E5 = make_float2(row0[i], has1 ? row1[i] : 0.0f);
        i = base + 6*h4;   E6 = make_float2(row0[i], has1 ? row1[i] : 0.0f);
        i = base + 7*h4;   E7 = make_float2(row0[i], has1 ? row1[i] : 0.0f);
      } else {
        E0 = z[ZI(base)];          E1 = z[ZI(base + h4)];
        E2 = z[ZI(base + 2*h4)];   E3 = z[ZI(base + 3*h4)];
        E4 = z[ZI(base + 4*h4)];   E5 = z[ZI(base + 5*h4)];
        E6 = z[ZI(base + 6*h4)];   E7 = z[ZI(base + 7*h4)];
      }
      float2 wa0 = tw[pos << (lg - s)];
      float2 wa1 = tw[(pos + h4) << (lg - s)];
      float2 wa2 = tw[(pos + 2*h4) << (lg - s)];
      float2 wa3 = tw[(pos + 3*h4) << (lg - s)];
      float2 wb0 = tw[pos << (lg - s + 1)];
      float2 wb1 = tw[(pos + h4) << (lg - s + 1)];
      float2 wc0 = tw[pos << (lg - s + 2)];
      float2 A0 = f2add(E0, E4), B0 = cmulc(f2sub(E0, E4), wa0);
      float2 A1 = f2add(E1, E5), B1 = cmulc(f2sub(E1, E5), wa1);
      float2 A2 = f2add(E2, E6), B2 = cmulc(f2sub(E2, E6), wa2);
      float2 A3 = f2add(E3, E7), B3 = cmulc(f2sub(E3, E7), wa3);
      float2 C0 = f2add(A0, A2), C2 = cmulc(f2sub(A0, A2), wb0);
      float2 C1 = f2add(A1, A3), C3 = cmulc(f2sub(A1, A3), wb1);
      float2 D0 = f2add(B0, B2), D2 = cmulc(f2sub(B0, B2), wb0);
      float2 D1 = f2add(B1, B3), D3 = cmulc(f2sub(B1, B3), wb1);
      z[ZI(base)]          = f2add(C0, C1);
      z[ZI(base + h4)]     = cmulc(f2sub(C0, C1), wc0);
      z[ZI(base + 2*h4)]   = f2add(C2, C3);
      z[ZI(base + 3*h4)]   = cmulc(f2sub(C2, C3), wc0);
      z[ZI(base + 4*h4)]   = f2add(D0, D1);
      z[ZI(base + 5*h4)]   = cmulc(f2sub(D0, D1), wc0);
      z[ZI(base + 6*h4)]   = f2add(D2, D3);
      z[ZI(base + 7*h4)]   = cmulc(f2sub(D2, D3), wc0);
    }
    __syncthreads();
  }
  {
    const float s1 = 1.0f / (float)L, s2 = 2.0f / (float)L;
    const int h = L >> 1;
    for (int q = t; q < (L >> 1); q += T) {
      int i0 = 2 * q, i1 = i0 + 1;
      float2 a = z[ZI(i0)], b = z[ZI(i1)];
      float2 u0 = f2add(a, b), u1 = f2sub(a, b);
      int k0 = (int)(__brev((unsigned)i0) >> (32 - lg));
      int k1 = (int)(__brev((unsigned)i1) >> (32 - lg));
      float sc0 = (k0 == 0 || k0 == h) ? s1 : (k0 < h ? s2 : 0.0f);
      float sc1 = (k1 == 0 || k1 == h) ? s1 : (k1 < h ? s2 : 0.0f);
      u0.x *= sc0; u0.y *= sc0; u1.x *= sc1; u1.y *= sc1;
      z[ZI(i0)] = f2add(u0, u1);
      z[ZI(i1)] = f2sub(u0, u1);
    }
  }
  __syncthreads();
  for (int s = 2; s + 2 <= lg; s += 3) {
    const int h = 1 << (s - 1);
    const int last = (s + 2 == lg) ? 1 : 0;
    for (int q = t; q < nq; q += T) {
      int pos = q & (h - 1);
      int base = ((q >> (s - 1)) << (s + 2)) + pos;
      float2 E0 = z[ZI(base)],         E1 = z[ZI(base + h)];
      float2 E2 = z[ZI(base + 2*h)],   E3 = z[ZI(base + 3*h)];
      float2 E4 = z[ZI(base + 4*h)],   E5 = z[ZI(base + 5*h)];
      float2 E6 = z[ZI(base + 6*h)],   E7 = z[ZI(base + 7*h)];
      float2 w0  = tw[pos << (lg - s)];
      float2 w10 = tw[pos << (lg - s - 1)];
      float2 w11 = tw[(pos + h) << (lg - s - 1)];
      float2 w20 = tw[pos << (lg - s - 2)];
      float2 w21 = tw[(pos + h) << (lg - s - 2)];
      float2 w22 = tw[(pos + 2*h) << (lg - s - 2)];
      float2 w23 = tw[(pos + 3*h) << (lg - s - 2)];
      float2 c;
      c = cmul(E1, w0); float2 A0 = f2add(E0, c), A1 = f2sub(E0, c);
      c = cmul(E3, w0); float2 A2 = f2add(E2, c), A3 = f2sub(E2, c);
      c = cmul(E5, w0); float2 A4 = f2add(E4, c), A5 = f2sub(E4, c);
      c = cmul(E7, w0); float2 A6 = f2add(E6, c), A7 = f2sub(E6, c);
      c = cmul(A2, w10); float2 B0 = f2add(A0, c), B2 = f2sub(A0, c);
      c = cmul(A3, w11); float2 B1 = f2add(A1, c), B3 = f2sub(A1, c);
      c = cmul(A6, w10); float2 B4 = f2add(A4, c), B6 = f2sub(A4, c);
      c = cmul(A7, w11); float2 B5 = f2add(A5, c), B7 = f2sub(A5, c);
      float2 F0, F1, F2, F3, F4, F5, F6, F7;
      c = cmul(B4, w20); F0 = f2add(B0, c); F4 = f2sub(B0, c);
      c = cmul(B5, w21); F1 = f2add(B1, c); F5 = f2sub(B1, c);
      c = cmul(B6, w22); F2 = f2add(B2, c); F6 = f2sub(B2, c);
      c = cmul(B7, w23); F3 = f2add(B3, c); F7 = f2sub(B3, c);
      if (last) {
        float2 ov[8] = {F0, F1, F2, F3, F4, F5, F6, F7};
#pragma unroll
        for (int j = 0; j < 8; ++j) {
          int i = base + j * h;
          float xa = row0[i];
          float xb = has1 ? row1[i] : 0.0f;
          float ha = ov[j].y - xb;
          float hb = xa - ov[j].x;
          row0[i] = atan2f(ha, xa);
          if (has1) row1[i] = atan2f(hb, xb);
        }
      } else {
        z[ZI(base)]        = F0; z[ZI(base + h)]    = F1;
        z[ZI(base + 2*h)]  = F2; z[ZI(base + 3*h)]  = F3;
        z[ZI(base + 4*h)]  = F4; z[ZI(base + 5*h)]  = F5;
        z[ZI(base + 6*h)]  = F6; z[ZI(base + 7*h)]  = F7;
      }
    }
    if (!last) __syncthreads();
  }
}

// ---------------- Hilbert radix-4 fallback (any lg) --------------------------
__global__ __launch_bounds__(512, 4) void k_hilbert4(float* __restrict__ sp,
    const float2* __restrict__ tw, int L, int lg, long M) {
  __shared__ float2 z[LMAX];  // 64KB
  long r0 = 2L * blockIdx.x;
  int has1 = (r0 + 1 < M) ? 1 : 0;
  float* row0 = sp + (size_t)r0 * L;
  float* row1 = row0 + (has1 ? (size_t)L : 0);
  const int t = threadIdx.x;
  const int T = 512;
  const int nq = L >> 2;

  {
    const int s = lg;
    const int h = 1 << (s - 1), h2 = h >> 1;
    for (int q = t; q < nq; q += T) {
      int pos = q & (h2 - 1);
      int base = ((q >> (s - 2)) << s) + pos;
      int i0 = base, i1 = base + h2, i2 = base + h, i3 = base + h + h2;
      float2 e0 = make_float2(row0[i0], has1 ? row1[i0] : 0.0f);
      float2 e1 = make_float2(row0[i1], has1 ? row1[i1] : 0.0f);
      float2 e2 = make_float2(row0[i2], has1 ? row1[i2] : 0.0f);
      float2 e3 = make_float2(row0[i3], has1 ? row1[i3] : 0.0f);
      float2 wa = tw[pos << (lg - s)];
      float2 wb = tw[(pos + h2) << (lg - s)];
      float2 wc = tw[pos << (lg - s + 1)];
      float2 t0 = f2add(e0, e2), t2 = cmulc(f2sub(e0, e2), wa);
      float2 t1 = f2add(e1, e3), t3 = cmulc(f2sub(e1, e3), wb);
      z[ZI(i0)] = f2add(t0, t1);
      z[ZI(i1)] = cmulc(f2sub(t0, t1), wc);
      z[ZI(i2)] = f2add(t2, t3);
      z[ZI(i3)] = cmulc(f2sub(t2, t3), wc);
    }
  }
  __syncthreads();
  for (int s = lg - 2; s >= 2; s -= 2) {
    const int h = 1 << (s - 1), h2 = h >> 1;
    for (int q = t; q < nq; q += T) {
      int pos = q & (h2 - 1);
      int base = ((q >> (s - 2)) << s) + pos;
      int i0 = base, i1 = base + h2, i2 = base + h, i3 = base + h + h2;
      float2 e0 = z[ZI(i0)], e1 = z[ZI(i1)], e2 = z[ZI(i2)], e3 = z[ZI(i3)];
      float2 wa = tw[pos << (lg - s)];
      float2 wb = tw[(pos + h2) << (lg - s)];
      float2 wc = tw[pos << (lg - s + 1)];
      float2 t0 = f2add(e0, e2), t2 = cmulc(f2sub(e0, e2), wa);
      float2 t1 = f2add(e1, e3), t3 = cmulc(f2sub(e1, e3), wb);
      z[ZI(i0)] = f2add(t0, t1);
      z[ZI(i1)] = cmulc(f2sub(t0, t1), wc);
      z[ZI(i2)] = f2add(t2, t3);
      z[ZI(i3)] = cmulc(f2sub(t2, t3), wc);
    }
    __syncthreads();
  }
  {
    const float s1 = 1.0f / (float)L, s2 = 2.0f / (float)L;
    const int h = L >> 1;
    if (lg & 1) {
      for (int q = t; q < (L >> 1); q += T) {
        int i0 = 2 * q, i1 = i0 + 1;
        float2 a = z[ZI(i0)], b = z[ZI(i1)];
        float2 u0 = f2add(a, b), u1 = f2sub(a, b);
        int k0 = (int)(__brev((unsigned)i0) >> (32 - lg));
        int k1 = (int)(__brev((unsigned)i1) >> (32 - lg));
        float sc0 = (k0 == 0 || k0 == h) ? s1 : (k0 < h ? s2 : 0.0f);
        float sc1 = (k1 == 0 || k1 == h) ? s1 : (k1 < h ? s2 : 0.0f);
        u0.x *= sc0; u0.y *= sc0; u1.x *= sc1; u1.y *= sc1;
        z[ZI(i0)] = f2add(u0, u1);
        z[ZI(i1)] = f2sub(u0, u1);
      }
    } else {
      for (int p = t; p < L; p += T) {
        int k = (int)(__brev((unsigned)p) >> (32 - lg));
        float sc = (k == 0 || k == h) ? s1 : (k < h ? s2 : 0.0f);
        float2 v = z[ZI(p)];
        v.x *= sc; v.y *= sc;
        z[ZI(p)] = v;
      }
    }
  }
  __syncthreads();
  const int s0 = (lg & 1) ? 2 : 1;
  for (int s = s0; s + 1 <= lg - 2; s += 2) {
    const int hs = 1 << (s - 1);
    for (int q = t; q < nq; q += T) {
      int pos = q & (hs - 1);
      int base = ((q >> (s - 1)) << (s + 1)) + pos;
      int i0 = base, i1 = base + hs, i2 = base + 2 * hs, i3 = base + 3 * hs;
      float2 e0 = z[ZI(i0)], e1 = z[ZI(i1)], e2 = z[ZI(i2)], e3 = z[ZI(i3)];
      float2 wa = tw[pos << (lg - s)];
      float2 wb = tw[pos << (lg - s - 1)];
      float2 wcc = tw[(pos + hs) << (lg - s - 1)];
      float2 c1 = cmul(e1, wa);
      float2 t0 = f2add(e0, c1), t1 = f2sub(e0, c1);
      float2 d1 = cmul(e3, wa);
      float2 t2 = f2add(e2, d1), t3 = f2sub(e2, d1);
      c1 = cmul(t2, wb);
      float2 o0 = f2add(t0, c1), o2 = f2sub(t0, c1);
      d1 = cmul(t3, wcc);
      float2 o1 = f2add(t1, d1), o3 = f2sub(t1, d1);
      z[ZI(i0)] = o0; z[ZI(i1)] = o1; z[ZI(i2)] = o2; z[ZI(i3)] = o3;
    }
    __syncthreads();
  }
  {
    const int s = lg - 1;
    const int hs = 1 << (s - 1);
    for (int q = t; q < nq; q += T) {
      int pos = q & (hs - 1);
      int base = ((q >> (s - 1)) << (s + 1)) + pos;
      int i0 = base, i1 = base + hs, i2 = base + 2 * hs, i3 = base + 3 * hs;
      float2 e0 = z[ZI(i0)], e1 = z[ZI(i1)], e2 = z[ZI(i2)], e3 = z[ZI(i3)];
      float2 wa = tw[pos << (lg - s)];
      float2 wb = tw[pos << (lg - s - 1)];
      float2 wcc = tw[(pos + hs) << (lg - s - 1)];
      float2 c1 = cmul(e1, wa);
      float2 t0 = f2add(e0, c1), t1 = f2sub(e0, c1);
      float2 d1 = cmul(e3, wa);
      float2 t2 = f2add(e2, d1), t3 = f2sub(e2, d1);
      c1 = cmul(t2, wb);
      float2 o0 = f2add(t0, c1), o2 = f2sub(t0, c1);
      d1 = cmul(t3, wcc);
      float2 o1 = f2add(t1, d1), o3 = f2sub(t1, d1);
      int idx[4] = {i0, i1, i2, i3};
      float2 ov[4] = {o0, o1, o2, o3};
#pragma unroll
      for (int j = 0; j < 4; ++j) {
        int i = idx[j];
        float xa = row0[i];
        float xb = has1 ? row1[i] : 0.0f;
        float2 w = ov[j];
        float ha = w.y - xb;
        float hb = xa - w.x;
        row0[i] = atan2f(ha, xa);
        if (has1) row1[i] = atan2f(hb, xb);
      }
    }
  }
}

// ---------------- unwrap fast path standalone (fallback) ---------------------
__global__ __launch_bounds__(256, 4) void k_unwrap_I32(
    const float* __restrict__ phase_all, const float* __restrict__ amp,
    const float* __restrict__ pf, bf16* __restrict__ I, int C, int L) {
  __shared__ float p[LMAX + LMAX / 32];  // skewed
  __shared__ int wsum[8];
  int bc = blockIdx.x, c = bc % C;
  int t = threadIdx.x;
  const float* prow = phase_all + (size_t)bc * L;
  for (int i = t; i < L; i += 256) p[i + (i >> 5)] = prow[i];
  __syncthreads();
  const int sbase = 33 * t;  // si(32*t)
  float v[32];
#pragma unroll
  for (int ii = 0; ii < 32; ++ii) v[ii] = p[sbase + ii];
  float prev = (t > 0) ? p[sbase - 2] : 0.0f;  // si(32t-1)
  int run = 0;
#pragma unroll
  for (int ii = 0; ii < 32; ++ii) {
    float cur = v[ii];
    if (ii > 0 || t > 0) {
      float d = cur - prev;
      int k = (int)floorf((d + PI_F) * (1.0f / TWO_PI_F));
      float m = d - TWO_PI_F * (float)k;
      if (m == -PI_F && d > 0.0f) k -= 1;
      run -= k;
    }
    prev = cur;
    v[ii] = cur + TWO_PI_F * (float)run;
  }
  int lane = t & 63, w = t >> 6;
  int inc = run;
#pragma unroll
  for (int off = 1; off < 64; off <<= 1) {
    int n = __shfl_up(inc, off);
    if (lane >= off) inc += n;
  }
  if (lane == 63) wsum[w] = inc;
  __syncthreads();
  int base = inc - run;
  for (int ww = 0; ww < w; ++ww) base += wsum[ww];
  float fb = TWO_PI_F * (float)base;
#pragma unroll
  for (int ii = 0; ii < 32; ++ii) v[ii] += fb;
#pragma unroll
  for (int ii = 0; ii < 32; ++ii) p[sbase + ii] = v[ii];
  __syncthreads();
  float hl[7], hr[7];
#pragma unroll
  for (int m = 0; m < 7; ++m)
    hl[m] = (t == 0) ? v[7 - m] : p[sbase - 8 + m];
#pragma unroll
  for (int m = 0; m < 7; ++m)
    hr[m] = (t == 255) ? v[30 - m] : p[sbase + 33 + m];
  __syncthreads();
  float wz[15];
  float mean = 0.0f;
#pragma unroll
  for (int j = 0; j < 15; ++j) { wz[j] = pf[4352 + c * 15 + j]; mean += wz[j]; }
  mean /= 15.0f;
#pragma unroll
  for (int j = 0; j < 15; ++j) wz[j] -= mean;
  float tanh_s = tanhf(pf[8960]);
  float phi0c = pf[8704 + c];
#pragma unroll
  for (int ii = 0; ii < 32; ++ii) {
    float delta = 0.0f;
#pragma unroll
    for (int j = 0; j < 15; ++j) {
      int idx = ii + j - 7;
      float u = (idx < 0) ? hl[idx + 7] : (idx >= 32 ? hr[idx - 32] : v[idx]);
      delta = fmaf(wz[j], u, delta);
    }
    float phi = v[ii] + tanh_s * delta + phi0c;
    p[sbase + ii] = cosf(phi);
  }
  __syncthreads();
  const float* arow = amp + (size_t)c * L;
  bf16* Irow = I + (size_t)bc * L;
  for (int i = t; i < L; i += 256)
    Irow[i] = f2b(arow[i] * p[i + (i >> 5)]);
}

// ---------------- unwrap legacy path (generic L, KP) -------------------------
__global__ __launch_bounds__(256) void k_unwrap_I(const float* __restrict__ phase_all,
    const float* __restrict__ amp, const float* __restrict__ pf,
    bf16* __restrict__ I, int C, int L, int KP) {
  __shared__ float p[LMAX];
  __shared__ int ksum[256];
  int bc = blockIdx.x;
  int c = bc % C;
  int t = threadIdx.x;
  int chunk = L >> 8;
  const float* prow = phase_all + (size_t)bc * L;
  for (int i = t; i < L; i += 256) p[i] = prow[i];
  __syncthreads();
  int start = t * chunk;
  float prev0 = (t > 0) ? p[start - 1] : 0.0f;
  int kacc = 0;
  {
    float prev = prev0;
    for (int ii = 0; ii < chunk; ++ii) {
      int i = start + ii;
      float cur = p[i];
      if (i > 0) {
        float d = cur - prev;
        int k = (int)floorf((d + PI_F) * (1.0f / TWO_PI_F));
        float m = d - TWO_PI_F * (float)k;
        if (m == -PI_F && d > 0.0f) k -= 1;
        kacc -= k;
      }
      prev = cur;
    }
  }
  ksum[t] = kacc;
  __syncthreads();
  if (t == 0) {
    int run = 0;
    for (int i = 0; i < 256; ++i) { int v = ksum[i]; ksum[i] = run; run += v; }
  }
  __syncthreads();
  {
    int run = ksum[t];
    float prev = prev0;
    for (int ii = 0; ii < chunk; ++ii) {
      int i = start + ii;
      float cur = p[i];
      if (i > 0) {
        float d = cur - prev;
        int k = (int)floorf((d + PI_F) * (1.0f / TWO_PI_F));
        float m = d - TWO_PI_F * (float)k;
        if (m == -PI_F && d > 0.0f) k -= 1;
        run -= k;
      }
      prev = cur;
      p[i] = cur + TWO_PI_F * (float)run;
    }
  }
  __syncthreads();
  float wz[32];
  float mean = 0.0f;
  for (int j = 0; j < KP; ++j) { wz[j] = pf[4352 + c * KP + j]; mean += wz[j]; }
  mean /= (float)KP;
  for (int j = 0; j < KP; ++j) wz[j] -= mean;
  int hk = KP / 2;
  float tanh_s = tanhf(pf[8960]);
  float phi0c = pf[8704 + c];
  const float* arow = amp + (size_t)c * L;
  bf16* Irow = I + (size_t)bc * L;
  for (int i = t; i < L; i += 256) {
    float delta = 0.0f;
    for (int j = 0; j < KP; ++j) {
      int idx = i + j - hk;
      idx = idx < 0 ? -idx : (idx >= L ? 2 * L - 2 - idx : idx);
      delta = fmaf(wz[j], p[idx], delta);
    }
    float phi = p[i] + tanh_s * delta + phi0c;
    Irow[i] = f2b(arow[i] * cosf(phi));
  }
}

// -------- MFMA GEMM, fused pair + split-K, double-buffered 2-phase ----------
// R9: + XCD-aware bijective block swizzle (T1). nwg = 704 = 8*88 exactly;
// after remap each XCD's 88 contiguous work-items cover 8 complete shared-B
// panels (2MB <= 4MB per-XCD L2) -> B-operand reads become L2 hits.
__global__ __launch_bounds__(256) void k_gemm_sk(const bf16* __restrict__ A0,
    const bf16* __restrict__ A1, const bf16* __restrict__ B0,
    const bf16* __restrict__ B1, float* __restrict__ part,
    int M, int L, int D, int KS, int KC) {
  __shared__ __align__(16) u16 As[2][128 * 32];
  __shared__ __align__(16) u16 Bs[2][128 * 32];
  // XCD swizzle: bijective when nwg % 8 == 0, else identity.
  int gx = gridDim.x, gy = gridDim.y, gz = gridDim.z;
  int lin = blockIdx.x + gx * (blockIdx.y + gy * blockIdx.z);
  int nwg = gx * gy * gz;
  if ((nwg & 7) == 0) {
    int qq = nwg >> 3;
    lin = (lin & 7) * qq + (lin >> 3);
  }
  int bx = lin % gx;
  int rem = lin / gx;
  int by = rem % gy;
  int zz = rem / gy;
  int g = zz / KS, ks = zz - g * KS;
  const u16* Ag = (const u16*)(g ? A1 : A0);
  const u16* Bg = (const u16*)(g ? B1 : B0);
  int m0 = bx * 128, n0 = by * 128;
  int t = threadIdx.x;
  int l = t & 63, w = t >> 6;
  int wm = (w >> 1) * 64, wn = (w & 1) * 64;
  int lr = l & 15, lq = l >> 4;
  f32x4 acc[4][4];
  f32x4 z4 = 0.0f;
  for (int i = 0; i < 4; ++i)
    for (int j = 0; j < 4; ++j) acc[i][j] = z4;

  int row = t >> 2, kc = t & 3;
  int ar = m0 + row; ar = ar < M ? ar : M - 1;
  int br = n0 + row; br = br < D ? br : D - 1;
  int row2 = (256 + t) >> 2, kc2 = t & 3;
  int ar2 = m0 + row2; ar2 = ar2 < M ? ar2 : M - 1;
  int br2 = n0 + row2; br2 = br2 < D ? br2 : D - 1;

  int kbeg = ks * KC, kend = kbeg + KC;
  auto STAGE = [&](int buf, int k0) {
    async16(Ag + (size_t)ar * L + (k0 + kc * 8), &As[buf][t * 8]);
    async16(Bg + (size_t)br * L + (k0 + kc * 8), &Bs[buf][t * 8]);
    async16(Ag + (size_t)ar2 * L + (k0 + kc2 * 8), &As[buf][(256 + t) * 8]);
    async16(Bg + (size_t)br2 * L + (k0 + kc2 * 8), &Bs[buf][(256 + t) * 8]);
  };
  STAGE(0, kbeg);
  int cur = 0;
  for (int k0 = kbeg; k0 < kend; k0 += 32) {
    __syncthreads();                       // buf[cur] staged; prior reads done
    if (k0 + 32 < kend) STAGE(cur ^ 1, k0 + 32);
    bf16x8 af[4], bfr[4];
#pragma unroll
    for (int i = 0; i < 4; ++i) {
      af[i]  = *(const bf16x8*)(&As[cur][(wm + i * 16 + lr) * 32 + lq * 8]);
      bfr[i] = *(const bf16x8*)(&Bs[cur][(wn + i * 16 + lr) * 32 + lq * 8]);
    }
#pragma unroll
    for (int i = 0; i < 4; ++i)
#pragma unroll
      for (int j = 0; j < 4; ++j)
        acc[i][j] = __builtin_amdgcn_mfma_f32_16x16x32_bf16(af[i], bfr[j], acc[i][j], 0, 0, 0);
    cur ^= 1;
  }
  float* pbase = part + (size_t)zz * M * D;
#pragma unroll
  for (int i = 0; i < 4; ++i) {
    int rowb = m0 + wm + i * 16 + lq * 4;
#pragma unroll
    for (int j = 0; j < 4; ++j) {
      int gcol = n0 + wn + j * 16 + lr;
      if (gcol < D) {
#pragma unroll
        for (int r = 0; r < 4; ++r) {
          int grow = rowb + r;
          if (grow < M)
            pbase[(size_t)grow * D + gcol] = acc[i][j][r];
        }
      }
    }
  }
}

// Vectorized reduce: float4 per thread over KS partials + bias + exact GELU.
__global__ __launch_bounds__(256) void k_reduce4(const float* __restrict__ part,
    const float* __restrict__ pf, float* __restrict__ out, long MD, int D, int KS) {
  long i4 = ((long)blockIdx.x * 256 + threadIdx.x) * 4;
  if (i4 >= 2 * MD) return;
  int g = (int)(i4 / MD);
  long r = i4 - (long)g * MD;
  const float* p = part + (size_t)g * KS * MD + r;
  float4 s = make_float4(0.f, 0.f, 0.f, 0.f);
  for (int ks = 0; ks < KS; ++ks) {
    float4 v = *(const float4*)(p + (size_t)ks * MD);
    s.x += v.x; s.y += v.y; s.z += v.z; s.w += v.w;
  }
  int d = (int)(r % (long)D);
  const float* bias = pf + g * 2048 + d;
  float vv[4] = {s.x, s.y, s.z, s.w};
  float4 o;
  float* po = (float*)&o;
#pragma unroll
  for (int j = 0; j < 4; ++j) {
    float v = vv[j] + bias[j];
    po[j] = 0.5f * v * (1.0f + erff(v * 0.70710678118654752f));
  }
  *(float4*)(out + i4) = o;
}

// Scalar fallback (D or MD not divisible by 4).
__global__ __launch_bounds__(256) void k_reduce(const float* __restrict__ part,
    const float* __restrict__ pf, float* __restrict__ out, long MD, int D, int KS) {
  long idx = (long)blockIdx.x * 256 + threadIdx.x;
  if (idx >= 2 * MD) return;
  int g = (int)(idx / MD);
  long r = idx - (long)g * MD;
  const float* p = part + (size_t)g * KS * MD + r;
  float s = 0.0f;
  for (int ks = 0; ks < KS; ++ks) s += p[(size_t)ks * MD];
  int d = (int)(r % (long)D);
  float v = s + pf[g * 2048 + d];
  out[idx] = 0.5f * v * (1.0f + erff(v * 0.70710678118654752f));
}

// ---------------- launcher ----------------
static inline int cdiv_i(long a, long b) { return (int)((a + b - 1) / b); }

extern "C" void kernel_launch(void* const* d_in, const int* in_sizes, int n_in,
                              void* d_out, int out_size, void* d_ws, size_t ws_size,
                              hipStream_t stream) {
  // Dict order: 0 x_input,1 x_w,2 x_b,3 i_w,4 i_b,5 log_sigma,6 pc_weight,
  // 7 pc_strength,8 alpha_log,9 phi0,10 b1,11 b2.  d_out is FLOAT32.
  long B = 64, C = 21, L = 8192, D = 512, KP = 15;
  if (n_in == 12) {
    long Sx = in_sizes[0], Sw = in_sizes[1], Sb = in_sizes[2];
    long Sls = in_sizes[5], Spw = in_sizes[6];
    if (Sb > 0 && Sw % Sb == 0 && Sls > 0 && Spw % Sls == 0) {
      long Lc = Sw / Sb, KPc = Spw / Sls;
      if (Lc >= 256 && Lc <= LMAX && !(Lc & (Lc - 1)) && (KPc & 1) && KPc <= 31 &&
          Sx % (Sls * Lc) == 0) {
        L = Lc; D = Sb; C = Sls; KP = KPc; B = Sx / (Sls * Lc);
      }
    }
  }
  long M = B * C;
  int lg = 0; while ((1L << lg) < L) ++lg;

  const void* x_input = d_in[0];
  const void* x_w     = d_in[1];
  const void* x_b     = d_in[2];
  const void* i_w     = d_in[3];
  const void* i_b     = d_in[4];
  const void* lsg     = d_in[5];
  const void* pw      = d_in[6];
  const void* ps      = d_in[7];
  const void* al      = d_in[8];
  const void* ph      = d_in[9];
  const void* b1      = d_in[10];
  const void* b2      = d_in[11];

  char* ws = (char*)d_ws;
  size_t off = 0;
  auto take = [&](size_t bytes) { size_t o = off; off = (off + bytes + 255) & ~(size_t)255; return o; };
  float*  seasonal = (float*)(ws + take((size_t)M * L * 4));
  float*  trend0   = (float*)(ws + take((size_t)C * L * 4));
  bf16*   Ibuf     = (bf16*)(ws + take((size_t)M * L * 2));
  float2* tw       = (float2*)(ws + take((size_t)(L / 2) * 8));
  float*  pf       = (float*)(ws + take(65536));
  int*    flag     = (int*)(ws + take(256));
  bf16*   Xb       = (bf16*)(ws + take((size_t)M * L * 2));
  bf16*   Btx      = (bf16*)(ws + take((size_t)D * L * 2));
  bf16*   Bti      = (bf16*)(ws + take((size_t)D * L * 2));
  if (ws_size < off) return;

  // split-K factor: largest pow2 <= 8 with K-chunks %32==0 and partials fitting
  // in the (dead-after-unwrap) seasonal buffer: 2*KS*D <= L.
  int KS = 8;
  while (KS > 1 && ((L % ((long)KS * 32)) != 0 || 2L * KS * D > L)) KS >>= 1;
  float* out0 = (float*)d_out;
  float* part = (2L * KS * D <= L) ? seasonal : out0;  // fallback: in-place, KS==1
  int KC = (int)(L / KS);

  k_params<<<64 + cdiv_i(L / 2, 256), 256, 0, stream>>>(
      x_b, i_b, lsg, pw, al, ph, ps, b1, b2, pf, flag, tw,
      (int)D, (int)C, (int)KP, (int)L);

  k_transpose2<<<dim3(cdiv_i(L, 64), cdiv_i(D, 64), 2), 256, 0, stream>>>(
      x_w, i_w, Btx, Bti, flag, (int)L, (int)D);

  if (L == 8192)
    k_decomp32<<<(int)M, 256, 0, stream>>>(x_input, flag, pf, seasonal, trend0, Xb,
                                           (int)C, (int)L);
  else
    k_decomp<<<(int)M, 256, 0, stream>>>(x_input, flag, pf, seasonal, trend0, Xb,
                                         (int)C, (int)L);

  bool fused = (L == 8192 && KP == 15 && ((lg - 1) % 3 == 0));
  if (fused) {
    k_hilbert_unwrap<<<cdiv_i(M, 2), 512, 0, stream>>>(
        seasonal, tw, trend0, pf, Ibuf, (int)C, (int)L, lg, M);
  } else {
    if ((lg - 1) % 3 == 0)
      k_hilbert8<<<cdiv_i(M, 2), 512, 0, stream>>>(seasonal, tw, (int)L, lg, M);
    else
      k_hilbert4<<<cdiv_i(M, 2), 512, 0, stream>>>(seasonal, tw, (int)L, lg, M);
    if (L == 8192 && KP == 15)
      k_unwrap_I32<<<(int)M, 256, 0, stream>>>(seasonal, trend0, pf, Ibuf, (int)C, (int)L);
    else
      k_unwrap_I<<<(int)M, 256, 0, stream>>>(seasonal, trend0, pf, Ibuf, (int)C, (int)L,
                                             (int)KP);
  }

  k_gemm_sk<<<dim3(cdiv_i(M, 128), cdiv_i(D, 128), 2 * KS), 256, 0, stream>>>(
      Xb, Ibuf, Btx, Bti, part, (int)M, (int)L, (int)D, KS, KC);
  if ((D % 4 == 0) && ((M * D) % 4 == 0))
    k_reduce4<<<cdiv_i(2 * M * D / 4, 256), 256, 0, stream>>>(part, pf, out0, M * D,
                                                              (int)D, KS);
  else
    k_reduce<<<cdiv_i(2 * M * D, 256), 256, 0, stream>>>(part, pf, out0, M * D,
                                                         (int)D, KS);
}